// Round 5
// baseline (117089.502 us; speedup 1.0000x reference)
//
#include <hip/hip_runtime.h>
#include <math.h>

__device__ __forceinline__ float gelu_f(float v) {
    return 0.5f * v * (1.0f + erff(v * 0.70710678118654752440f));
}

// ---------------------------------------------------------------------------
// Diagnostic dump: every output element = code*1e6 + val (f32-exact <1.6e7)
// ---------------------------------------------------------------------------
__global__ void dump_k(float* __restrict__ out, int n, float val) {
    int t = blockIdx.x * 256 + threadIdx.x;
    if (t < n) out[t] = val;
}

// ---------------------------------------------------------------------------
// Patch embed + cls + pos. grid (N, B), block 256. LDS variant (patch fits).
// ---------------------------------------------------------------------------
__global__ void embed_lds_k(const float* __restrict__ src, const float* __restrict__ cw,
                            const float* __restrict__ cb, const float* __restrict__ pos,
                            const float* __restrict__ cls, float* __restrict__ x,
                            int C, int IMG, int P, int m, int E, int N, int K) {
    extern __shared__ float patch[];
    int n = blockIdx.x, b = blockIdx.y, t = threadIdx.x;
    if (n == 0) {
        for (int e = t; e < E; e += 256)
            x[((size_t)b * N) * E + e] = cls[e] + pos[e];
        return;
    }
    int p = n - 1, ph = p / m, pw = p % m;
    int P2 = P * P;
    for (int mm = t; mm < K; mm += 256) {
        int c = mm / P2, rem = mm % P2, i = rem / P, j = rem % P;
        patch[mm] = src[(((size_t)b * C + c) * IMG + ph * P + i) * IMG + pw * P + j];
    }
    __syncthreads();
    for (int e = t; e < E; e += 256) {
        float acc = cb[e];
        const float* wr = cw + (size_t)e * K;
        for (int mm = 0; mm < K; ++mm) acc += patch[mm] * wr[mm];
        x[((size_t)b * N + n) * E + e] = acc + pos[(size_t)n * E + e];
    }
}

// Fallback: no LDS (huge patches) — direct global reads.
__global__ void embed_dir_k(const float* __restrict__ src, const float* __restrict__ cw,
                            const float* __restrict__ cb, const float* __restrict__ pos,
                            const float* __restrict__ cls, float* __restrict__ x,
                            int C, int IMG, int P, int m, int E, int N, int K) {
    int n = blockIdx.x, b = blockIdx.y, t = threadIdx.x;
    if (n == 0) {
        for (int e = t; e < E; e += 256)
            x[((size_t)b * N) * E + e] = cls[e] + pos[e];
        return;
    }
    int p = n - 1, ph = p / m, pw = p % m;
    int P2 = P * P;
    for (int e = t; e < E; e += 256) {
        float acc = cb[e];
        const float* wr = cw + (size_t)e * K;
        for (int mm = 0; mm < K; ++mm) {
            int c = mm / P2, rem = mm % P2, i = rem / P, j = rem % P;
            acc += src[(((size_t)b * C + c) * IMG + ph * P + i) * IMG + pw * P + j] * wr[mm];
        }
        x[((size_t)b * N + n) * E + e] = acc + pos[(size_t)n * E + e];
    }
}

// ---------------------------------------------------------------------------
// LayerNorm rows of x -> xg. grid ceil(TOK/4), block 256 (4 rows x 64 lanes).
// g,b pre-offset by layer on host.
// ---------------------------------------------------------------------------
__global__ void ln_k(const float* __restrict__ x, const float* __restrict__ g,
                     const float* __restrict__ b, float* __restrict__ xg,
                     int TOK, int E, float invE) {
    int row = blockIdx.x * 4 + (threadIdx.x >> 6);
    int lane = threadIdx.x & 63;
    if (row >= TOK) return;
    const float* xr = x + (size_t)row * E;
    float s = 0.f;
    for (int e = lane; e < E; e += 64) s += xr[e];
#pragma unroll
    for (int mm = 32; mm >= 1; mm >>= 1) s += __shfl_xor(s, mm, 64);
    float mean = s * invE;
    float v = 0.f;
    for (int e = lane; e < E; e += 64) { float d = xr[e] - mean; v += d * d; }
#pragma unroll
    for (int mm = 32; mm >= 1; mm >>= 1) v += __shfl_xor(v, mm, 64);
    float inv = rsqrtf(v * invE + 1e-5f);
    float* orow = xg + (size_t)row * E;
    for (int e = lane; e < E; e += 64) orow[e] = (xr[e] - mean) * inv * g[e] + b[e];
}

// ---------------------------------------------------------------------------
// Block-diagonal attention (BS=8), per-head loop. grid (G, B), block 256.
// Weights pre-offset by layer on host. LDS: q,k,v [8][HD] + sc[64].
// ---------------------------------------------------------------------------
__global__ void attn_k(const float* __restrict__ Wq, const float* __restrict__ bq,
                       const float* __restrict__ Wk, const float* __restrict__ bk,
                       const float* __restrict__ Wv, const float* __restrict__ bv,
                       const float* __restrict__ fp, const float* __restrict__ xg,
                       float* __restrict__ x, int N, int E, int H, int HD, float rscale) {
    extern __shared__ float sm[];
    float* q = sm;
    float* k = q + 8 * HD;
    float* v = k + 8 * HD;
    float* sc = v + 8 * HD;   // 64 floats
    int g = blockIdx.x, b = blockIdx.y, t = threadIdx.x;
    int t0 = g * 8;
    int nv = min(8, N - t0);
    const float* xrow = xg + ((size_t)b * N + t0) * E;

    for (int h = 0; h < H; ++h) {
        // ---- qkv for this head's columns
        for (int i = t; i < HD; i += 256) {
            int col = h * HD + i;
            float aq[8], ak[8], av[8];
            float bqv = bq[col], bkv = bk[col], bvv = bv[col];
#pragma unroll
            for (int r = 0; r < 8; ++r) { aq[r] = bqv; ak[r] = bkv; av[r] = bvv; }
            for (int kk = 0; kk < E; ++kk) {
                float wq = Wq[(size_t)kk * E + col];
                float wk = Wk[(size_t)kk * E + col];
                float wv = Wv[(size_t)kk * E + col];
#pragma unroll
                for (int r = 0; r < 8; ++r) {
                    if (r < nv) {
                        float xv = xrow[(size_t)r * E + kk];
                        aq[r] += xv * wq; ak[r] += xv * wk; av[r] += xv * wv;
                    }
                }
            }
#pragma unroll
            for (int r = 0; r < 8; ++r)
                if (r < nv) { q[r * HD + i] = aq[r]; k[r * HD + i] = ak[r]; v[r * HD + i] = av[r]; }
        }
        __syncthreads();
        // ---- fproj on q,k (per row, in place via registers; HD <= 1024)
        for (int r = 0; r < nv; ++r) {
            float rq0 = 0.f, rk0 = 0.f, rq1 = 0.f, rk1 = 0.f, rq2 = 0.f, rk2 = 0.f, rq3 = 0.f, rk3 = 0.f;
            {
                int i0 = t, i1 = t + 256, i2 = t + 512, i3 = t + 768;
                for (int d = 0; d < HD; ++d) {
                    float qv = q[r * HD + d], kv = k[r * HD + d];
                    const float* fr = fp + (size_t)d * HD;
                    if (i0 < HD) { float f0 = fr[i0]; rq0 += qv * f0; rk0 += kv * f0; }
                    if (i1 < HD) { float f1 = fr[i1]; rq1 += qv * f1; rk1 += kv * f1; }
                    if (i2 < HD) { float f2 = fr[i2]; rq2 += qv * f2; rk2 += kv * f2; }
                    if (i3 < HD) { float f3 = fr[i3]; rq3 += qv * f3; rk3 += kv * f3; }
                }
            }
            __syncthreads();
            if (t < HD)       { q[r * HD + t] = rq0;       k[r * HD + t] = rk0; }
            if (t + 256 < HD) { q[r * HD + t + 256] = rq1; k[r * HD + t + 256] = rk1; }
            if (t + 512 < HD) { q[r * HD + t + 512] = rq2; k[r * HD + t + 512] = rk2; }
            if (t + 768 < HD) { q[r * HD + t + 768] = rq3; k[r * HD + t + 768] = rk3; }
            __syncthreads();
        }
        // ---- scores 8x8
        if (t < 64) {
            int qr = t >> 3, kr = t & 7;
            if (qr < nv && kr < nv) {
                float s = 0.f;
                for (int d = 0; d < HD; ++d) s += q[qr * HD + d] * k[kr * HD + d];
                sc[t] = s * rscale;
            }
        }
        __syncthreads();
        // ---- softmax rows
        if (t < 8 && t < nv) {
            float mx = -1e30f;
            for (int kk = 0; kk < nv; ++kk) mx = fmaxf(mx, sc[t * 8 + kk]);
            float sum = 0.f;
            for (int kk = 0; kk < nv; ++kk) { float e = expf(sc[t * 8 + kk] - mx); sc[t * 8 + kk] = e; sum += e; }
            float inv = 1.f / sum;
            for (int kk = 0; kk < nv; ++kk) sc[t * 8 + kk] *= inv;
        }
        __syncthreads();
        // ---- PV + residual
        for (int i = t; i < HD; i += 256) {
            int col = h * HD + i;
            for (int r = 0; r < nv; ++r) {
                float o = 0.f;
                for (int kk = 0; kk < nv; ++kk) o += sc[r * 8 + kk] * v[kk * HD + i];
                x[((size_t)b * N + t0 + r) * E + col] += o;
            }
        }
        __syncthreads();
    }
}

// ---------------------------------------------------------------------------
// FF1: xg@W1+b1 -> gelu -> hf. grid (ceil(ntok/32), ceil(FF/128)), block 256.
// W1,b1 pre-offset by layer.
// ---------------------------------------------------------------------------
__global__ void ff1_k(const float* __restrict__ W1, const float* __restrict__ b1,
                      const float* __restrict__ xg, float* __restrict__ hf,
                      int tok0, int TOK, int E, int FF) {
    __shared__ float xs[32][128];
    int t = threadIdx.x;
    int m0 = tok0 + blockIdx.x * 32;
    int c0 = blockIdx.y * 128;
    int j = t & 127, rh = t >> 7;
    int col = c0 + j;
    float acc[16];
#pragma unroll
    for (int r = 0; r < 16; ++r) acc[r] = 0.f;
    for (int k0 = 0; k0 < E; k0 += 128) {
        __syncthreads();
        for (int idx = t; idx < 32 * 128; idx += 256) {
            int rr = idx >> 7, cc = idx & 127;
            int tok = m0 + rr;
            xs[rr][cc] = (tok < TOK && k0 + cc < E) ? xg[(size_t)tok * E + k0 + cc] : 0.f;
        }
        __syncthreads();
        int kmax = min(128, E - k0);
        if (col < FF) {
            for (int kk = 0; kk < kmax; ++kk) {
                float w = W1[(size_t)(k0 + kk) * FF + col];
#pragma unroll
                for (int r = 0; r < 16; ++r) acc[r] += xs[rh * 16 + r][kk] * w;
            }
        }
    }
    if (col < FF) {
        float bias = b1[col];
#pragma unroll
        for (int r = 0; r < 16; ++r) {
            int tok = m0 + rh * 16 + r;
            if (tok < TOK) hf[(size_t)(tok - tok0) * FF + col] = gelu_f(acc[r] + bias);
        }
    }
}

// ---------------------------------------------------------------------------
// FF2: hf@W2+b2 + residual into x. grid (ceil(ntok/32), ceil(E/32)), block 256.
// ---------------------------------------------------------------------------
__global__ void ff2_k(const float* __restrict__ W2, const float* __restrict__ b2,
                      const float* __restrict__ hf, float* __restrict__ x,
                      int tok0, int TOK, int E, int FF) {
    __shared__ float hs[32][128];
    int t = threadIdx.x;
    int m0 = tok0 + blockIdx.x * 32;
    int c0 = blockIdx.y * 32;
    int j = t & 31, rg = t >> 5;
    int col = c0 + j;
    float acc[4] = {0.f, 0.f, 0.f, 0.f};
    for (int k0 = 0; k0 < FF; k0 += 128) {
        __syncthreads();
        for (int idx = t; idx < 32 * 128; idx += 256) {
            int rr = idx >> 7, cc = idx & 127;
            int tok = m0 + rr;
            hs[rr][cc] = (tok < TOK && k0 + cc < FF) ? hf[(size_t)(tok - tok0) * FF + k0 + cc] : 0.f;
        }
        __syncthreads();
        int kmax = min(128, FF - k0);
        if (col < E) {
            for (int kk = 0; kk < kmax; ++kk) {
                float w = W2[(size_t)(k0 + kk) * E + col];
#pragma unroll
                for (int r = 0; r < 4; ++r) acc[r] += hs[rg * 4 + r][kk] * w;
            }
        }
    }
    if (col < E) {
        float bias = b2[col];
#pragma unroll
        for (int r = 0; r < 4; ++r) {
            int tok = m0 + rg * 4 + r;
            if (tok < TOK) x[(size_t)tok * E + col] += acc[r] + bias;
        }
    }
}

// ---------------------------------------------------------------------------
// Head: x[:,0] @ fc_w + fc_b
// ---------------------------------------------------------------------------
__global__ void head_k(const float* __restrict__ fw, const float* __restrict__ fb,
                       const float* __restrict__ x, float* __restrict__ out,
                       int Bc, int N, int E, int NC) {
    int idx = blockIdx.x * 256 + threadIdx.x;
    if (idx < Bc * NC) {
        int b = idx / NC, nc = idx % NC;
        float acc = fb[nc];
        const float* xr = x + (size_t)b * N * E;
        for (int e = 0; e < E; ++e) acc += xr[e] * fw[(size_t)e * NC + nc];
        out[idx] = acc;
    }
}

// ---------------------------------------------------------------------------
static int isqrt_i(long long v) {
    if (v < 0) return -1;
    long long r = (long long)(sqrt((double)v) + 0.5);
    while (r * r > v) --r;
    while ((r + 1) * (r + 1) <= v) ++r;
    return (int)r;
}

extern "C" void kernel_launch(void* const* d_in, const int* in_sizes, int n_in,
                              void* d_out, int out_size, void* d_ws, size_t ws_size,
                              hipStream_t stream) {
    float* out = (float*)d_out;
    int nblk_out = (out_size + 255) / 256;
#define DUMP(code, val) do { \
        dump_k<<<nblk_out, 256, 0, stream>>>(out, out_size, (float)((code) * 1000000.0 + (double)(val))); \
        return; } while (0)

    if (n_in != 22) DUMP(1, n_in < 999999 ? n_in : 999999);
    const int* S = in_sizes;

    int E = S[2];
    if (E <= 0 || S[4] != E) DUMP(2, 4);
    if (S[6] % E) DUMP(2, 6);
    int L = S[6] / E;
    if (L <= 0) DUMP(2, 6);
    // size-model checks
    long long EE = (long long)E * E;
    if (S[5] != L * EE) DUMP(2, 5);
    if (S[7] != L * EE) DUMP(2, 7);
    if (S[9] != L * EE) DUMP(2, 9);
    if (S[8] != L * E || S[10] != L * E) DUMP(2, 8);
    if (S[12] != L * E || S[13] != L * E || S[14] != L * E || S[15] != L * E) DUMP(2, 12);
    if (S[19] != L * E) DUMP(2, 19);
    if (S[11] % L) DUMP(2, 11);
    int HD = isqrt_i(S[11] / L);
    if ((long long)HD * HD * L != S[11] || HD <= 0 || E % HD) DUMP(3, HD > 0 ? HD : 0);
    int H = E / HD;
    if (S[17] % L) DUMP(2, 17);
    int FF = S[17] / L;
    if (S[16] != (long long)L * E * FF) DUMP(2, 16);
    if (S[18] != (long long)L * FF * E) DUMP(2, 18);
    if (S[3] % E) DUMP(2, 3);
    int N = S[3] / E;
    int m = isqrt_i(N - 1);
    if (m <= 0 || m * m != N - 1) DUMP(4, N < 999999 ? N : 999999);
    int NC = S[21];
    if (NC <= 0 || S[20] != (long long)E * NC) DUMP(2, 20);
    if (out_size % NC) DUMP(8, out_size < 999999 ? out_size : 999999);
    int Bc = out_size / NC;
    if (S[1] % E) DUMP(2, 1);
    int K = S[1] / E;
    // resolve (C, P): C*P^2 == K, P integer; priority order
    static const int corder[12] = {3, 4, 1, 2, 8, 16, 6, 12, 32, 64, 24, 48};
    int C = -1, P = -1;
    for (int ci = 0; ci < 12; ++ci) {
        int c = corder[ci];
        if (K % c) continue;
        int p = isqrt_i(K / c);
        if (p > 0 && p * p * c == K) {
            // src consistency: B*C*(P*m)^2 == S[0]
            long long img = (long long)p * m;
            if ((long long)Bc * c * img * img == S[0]) { C = c; P = p; break; }
        }
    }
    if (C < 0) DUMP(5, K < 999999 ? K : 999999);
    int IMG = P * m;
    int TOK = Bc * N;
    int Gg = (N + 7) / 8;

    // attention LDS
    size_t attn_sh = (size_t)(24 * HD + 64) * sizeof(float);
    if (attn_sh > 64000) DUMP(7, HD);

    // workspace layout: x[TOK*E], xg[TOK*E], hf[CH*FF]
    size_t base_f = 2 * (size_t)TOK * E;
    if (ws_size < (base_f + 32 * (size_t)FF) * 4) DUMP(6, (double)(ws_size >> 20));
    size_t avail_f = ws_size / 4 - base_f;
    long long CH = (long long)(avail_f / FF);
    if (CH > TOK) CH = TOK;
    CH = (CH / 32) * 32;
    if (CH < 32) DUMP(6, (double)(ws_size >> 20));

    float* x  = (float*)d_ws;
    float* xg = x + (size_t)TOK * E;
    float* hf = xg + (size_t)TOK * E;

    const float* src = (const float*)d_in[0];
    const float* cw  = (const float*)d_in[1];
    const float* cb  = (const float*)d_in[2];
    const float* pos = (const float*)d_in[3];
    const float* cls = (const float*)d_in[4];
    const float* Wq  = (const float*)d_in[5];
    const float* bq  = (const float*)d_in[6];
    const float* Wk  = (const float*)d_in[7];
    const float* bk  = (const float*)d_in[8];
    const float* Wv  = (const float*)d_in[9];
    const float* bv  = (const float*)d_in[10];
    const float* fp  = (const float*)d_in[11];
    const float* g1  = (const float*)d_in[12];
    const float* b1  = (const float*)d_in[13];
    const float* g2  = (const float*)d_in[14];
    const float* b2  = (const float*)d_in[15];
    const float* w1  = (const float*)d_in[16];
    const float* bb1 = (const float*)d_in[17];
    const float* w2  = (const float*)d_in[18];
    const float* bb2 = (const float*)d_in[19];
    const float* fcw = (const float*)d_in[20];
    const float* fcb = (const float*)d_in[21];

    float invE = 1.f / (float)E;
    float rscale = 1.f / sqrtf((float)HD);

    // embed
    size_t patch_sh = (size_t)K * sizeof(float);
    if (patch_sh <= 48000)
        embed_lds_k<<<dim3(N, Bc), 256, patch_sh, stream>>>(src, cw, cb, pos, cls, x,
                                                            C, IMG, P, m, E, N, K);
    else
        embed_dir_k<<<dim3(N, Bc), 256, 0, stream>>>(src, cw, cb, pos, cls, x,
                                                     C, IMG, P, m, E, N, K);

    int ln_grid = (TOK + 3) / 4;
    for (int l = 0; l < L; ++l) {
        ln_k<<<ln_grid, 256, 0, stream>>>(x, g1 + (size_t)l * E, b1 + (size_t)l * E,
                                          xg, TOK, E, invE);
        attn_k<<<dim3(Gg, Bc), 256, attn_sh, stream>>>(
            Wq + (size_t)l * E * E, bq + (size_t)l * E,
            Wk + (size_t)l * E * E, bk + (size_t)l * E,
            Wv + (size_t)l * E * E, bv + (size_t)l * E,
            fp + (size_t)l * HD * HD, xg, x, N, E, H, HD, rscale);
        ln_k<<<ln_grid, 256, 0, stream>>>(x, g2 + (size_t)l * E, b2 + (size_t)l * E,
                                          xg, TOK, E, invE);
        for (long long tok0 = 0; tok0 < TOK; tok0 += CH) {
            long long ntok = TOK - tok0 < CH ? TOK - tok0 : CH;
            int gx = (int)((ntok + 31) / 32);
            ff1_k<<<dim3(gx, (FF + 127) / 128), 256, 0, stream>>>(
                w1 + (size_t)l * E * FF, bb1 + (size_t)l * FF, xg, hf,
                (int)tok0, TOK, E, FF);
            ff2_k<<<dim3(gx, (E + 31) / 32), 256, 0, stream>>>(
                w2 + (size_t)l * FF * E, bb2 + (size_t)l * E, hf, x,
                (int)tok0, TOK, E, FF);
        }
    }
    head_k<<<nblk_out, 256, 0, stream>>>(fcw, fcb, x, out, Bc, N, E, NC);
#undef DUMP
}

// Round 6
// 26783.652 us; speedup vs baseline: 4.3717x; 4.3717x over previous
//
#include <hip/hip_runtime.h>
#include <hip/hip_bf16.h>
#include <math.h>

typedef __attribute__((ext_vector_type(8))) short short8v;
typedef __attribute__((ext_vector_type(4))) short short4v;
typedef __attribute__((ext_vector_type(4))) float float4v;

__device__ __forceinline__ float gelu_f(float v) {
    return 0.5f * v * (1.0f + erff(v * 0.70710678118654752440f));
}

__device__ __forceinline__ short bf16r(float f) {
    unsigned u = __float_as_uint(f);
    u += 0x7FFFu + ((u >> 16) & 1u);
    return (short)(u >> 16);
}

// ---------------------------------------------------------------------------
// Diagnostic dump
// ---------------------------------------------------------------------------
__global__ void dump_k(float* __restrict__ out, int n, float val) {
    int t = blockIdx.x * 256 + threadIdx.x;
    if (t < n) out[t] = val;
}

// ---------------------------------------------------------------------------
// Generic bf16-MFMA GEMM: C[M,N] (f32) = op(A[M,K] @ B[K,N] + bias)
// A,B f32 global, converted to bf16 on LDS stage. f32 accumulate.
// Tile 64x64x64, 256 threads (4 waves); wave w owns rows w*16..w*16+15.
// op: 0 = store, 1 = gelu+store, 2 = add into C (residual).
// ---------------------------------------------------------------------------
#define BM 64
#define BN 64
#define BKT 64

__global__ __launch_bounds__(256) void gemm_k(
        const float* __restrict__ A, int lda,
        const float* __restrict__ Bm, int ldb,
        float* __restrict__ C, int ldc,
        const float* __restrict__ bias,
        int M, int Nn, int K, int op) {
    __shared__ short Abf[BM][BKT + 8];
    __shared__ short Bbf[BN][BKT + 8];
    int t = threadIdx.x;
    int m0 = blockIdx.x * BM, n0 = blockIdx.y * BN;
    int w = t >> 6, lane = t & 63;
    int lrow = lane & 15, lk = lane >> 4;
    float4v acc[4];
#pragma unroll
    for (int c = 0; c < 4; ++c) acc[c] = (float4v){0.f, 0.f, 0.f, 0.f};

    int ar = t >> 4, ac = (t & 15) * 4;

    for (int k0 = 0; k0 < K; k0 += BKT) {
        __syncthreads();
        // ---- stage A [64 rows x 64 k] -> bf16
#pragma unroll
        for (int i = 0; i < 4; ++i) {
            int row = ar + i * 16;
            int gr = m0 + row, gk = k0 + ac;
            short4v v;
            if (gr < M && gk + 4 <= K) {
                const float* p = A + (size_t)gr * lda + gk;
                v.x = bf16r(p[0]); v.y = bf16r(p[1]);
                v.z = bf16r(p[2]); v.w = bf16r(p[3]);
            } else {
                float e0 = (gr < M && gk + 0 < K) ? A[(size_t)gr * lda + gk + 0] : 0.f;
                float e1 = (gr < M && gk + 1 < K) ? A[(size_t)gr * lda + gk + 1] : 0.f;
                float e2 = (gr < M && gk + 2 < K) ? A[(size_t)gr * lda + gk + 2] : 0.f;
                float e3 = (gr < M && gk + 3 < K) ? A[(size_t)gr * lda + gk + 3] : 0.f;
                v.x = bf16r(e0); v.y = bf16r(e1); v.z = bf16r(e2); v.w = bf16r(e3);
            }
            *(short4v*)&Abf[row][ac] = v;
        }
        // ---- stage B [64 k x 64 n] transposed -> Bbf[n][k] bf16
#pragma unroll
        for (int i = 0; i < 4; ++i) {
            int kr = ar + i * 16;
            int gk = k0 + kr;
            float p0 = 0.f, p1 = 0.f, p2 = 0.f, p3 = 0.f;
            if (gk < K) {
                const float* p = Bm + (size_t)gk * ldb + n0 + ac;
                if (n0 + ac + 4 <= Nn) { p0 = p[0]; p1 = p[1]; p2 = p[2]; p3 = p[3]; }
                else {
                    if (n0 + ac + 0 < Nn) p0 = p[0];
                    if (n0 + ac + 1 < Nn) p1 = p[1];
                    if (n0 + ac + 2 < Nn) p2 = p[2];
                    if (n0 + ac + 3 < Nn) p3 = p[3];
                }
            }
            Bbf[ac + 0][kr] = bf16r(p0);
            Bbf[ac + 1][kr] = bf16r(p1);
            Bbf[ac + 2][kr] = bf16r(p2);
            Bbf[ac + 3][kr] = bf16r(p3);
        }
        __syncthreads();
        // ---- MFMA: 2 k-steps of 32
#pragma unroll
        for (int ks = 0; ks < 2; ++ks) {
            short8v af = *(const short8v*)&Abf[w * 16 + lrow][ks * 32 + lk * 8];
#pragma unroll
            for (int c = 0; c < 4; ++c) {
                short8v bfv = *(const short8v*)&Bbf[c * 16 + lrow][ks * 32 + lk * 8];
                acc[c] = __builtin_amdgcn_mfma_f32_16x16x32_bf16(af, bfv, acc[c], 0, 0, 0);
            }
        }
    }
    // ---- epilogue: C/D map col=lane&15, row=(lane>>4)*4+reg (verified)
#pragma unroll
    for (int c = 0; c < 4; ++c) {
        int col = n0 + c * 16 + lrow;
        if (col >= Nn) continue;
        float bb = bias ? bias[col] : 0.f;
#pragma unroll
        for (int q = 0; q < 4; ++q) {
            int row = m0 + w * 16 + lk * 4 + q;
            if (row < M) {
                float v = acc[c][q] + bb;
                float* cp = C + (size_t)row * ldc + col;
                if (op == 1) *cp = gelu_f(v);
                else if (op == 2) *cp += v;
                else *cp = v;
            }
        }
    }
}

// ---------------------------------------------------------------------------
// Copy Wv into the V slot of Wqkv
// ---------------------------------------------------------------------------
__global__ void copyv_k(const float* __restrict__ Wv, float* __restrict__ Wqkv, int E) {
    size_t idx = (size_t)blockIdx.x * 256 + threadIdx.x;
    size_t tot = (size_t)E * E;
    if (idx < tot) {
        size_t i = idx / E, c = idx % E;
        Wqkv[i * 3 * E + 2 * E + c] = Wv[idx];
    }
}

// ---------------------------------------------------------------------------
// Fold biases: bqkv[0:E]=bq@fp per head, [E:2E]=bk@fp, [2E:3E]=bv
// ---------------------------------------------------------------------------
__global__ void biasfold_k(const float* __restrict__ bq, const float* __restrict__ bk,
                           const float* __restrict__ bv, const float* __restrict__ fp,
                           float* __restrict__ bqkv, int E, int HD) {
    int c = blockIdx.x * 256 + threadIdx.x;
    if (c >= 3 * E) return;
    if (c < 2 * E) {
        int mat = c / E, cc = c % E, h = cc / HD, j = cc % HD;
        const float* bb = mat ? bk : bq;
        float s = 0.f;
        for (int d = 0; d < HD; ++d) s += bb[h * HD + d] * fp[(size_t)d * HD + j];
        bqkv[c] = s;
    } else {
        bqkv[c] = bv[c - 2 * E];
    }
}

// ---------------------------------------------------------------------------
// Patch embed + cls + pos. grid (N, B), block 256.
// ---------------------------------------------------------------------------
__global__ void embed_lds_k(const float* __restrict__ src, const float* __restrict__ cw,
                            const float* __restrict__ cb, const float* __restrict__ pos,
                            const float* __restrict__ cls, float* __restrict__ x,
                            int C, int IMG, int P, int m, int E, int N, int K) {
    extern __shared__ float patch[];
    int n = blockIdx.x, b = blockIdx.y, t = threadIdx.x;
    if (n == 0) {
        for (int e = t; e < E; e += 256)
            x[((size_t)b * N) * E + e] = cls[e] + pos[e];
        return;
    }
    int p = n - 1, ph = p / m, pw = p % m;
    int P2 = P * P;
    for (int mm = t; mm < K; mm += 256) {
        int c = mm / P2, rem = mm % P2, i = rem / P, j = rem % P;
        patch[mm] = src[(((size_t)b * C + c) * IMG + ph * P + i) * IMG + pw * P + j];
    }
    __syncthreads();
    for (int e = t; e < E; e += 256) {
        float acc = cb[e];
        const float* wr = cw + (size_t)e * K;
        for (int mm = 0; mm < K; ++mm) acc += patch[mm] * wr[mm];
        x[((size_t)b * N + n) * E + e] = acc + pos[(size_t)n * E + e];
    }
}

__global__ void embed_dir_k(const float* __restrict__ src, const float* __restrict__ cw,
                            const float* __restrict__ cb, const float* __restrict__ pos,
                            const float* __restrict__ cls, float* __restrict__ x,
                            int C, int IMG, int P, int m, int E, int N, int K) {
    int n = blockIdx.x, b = blockIdx.y, t = threadIdx.x;
    if (n == 0) {
        for (int e = t; e < E; e += 256)
            x[((size_t)b * N) * E + e] = cls[e] + pos[e];
        return;
    }
    int p = n - 1, ph = p / m, pw = p % m;
    int P2 = P * P;
    for (int e = t; e < E; e += 256) {
        float acc = cb[e];
        const float* wr = cw + (size_t)e * K;
        for (int mm = 0; mm < K; ++mm) {
            int c = mm / P2, rem = mm % P2, i = rem / P, j = rem % P;
            acc += src[(((size_t)b * C + c) * IMG + ph * P + i) * IMG + pw * P + j] * wr[mm];
        }
        x[((size_t)b * N + n) * E + e] = acc + pos[(size_t)n * E + e];
    }
}

// ---------------------------------------------------------------------------
// LayerNorm rows of x -> xg. grid ceil(TOK/4), block 256.
// ---------------------------------------------------------------------------
__global__ void ln_k(const float* __restrict__ x, const float* __restrict__ g,
                     const float* __restrict__ b, float* __restrict__ xg,
                     int TOK, int E, float invE) {
    int row = blockIdx.x * 4 + (threadIdx.x >> 6);
    int lane = threadIdx.x & 63;
    if (row >= TOK) return;
    const float* xr = x + (size_t)row * E;
    float s = 0.f;
    for (int e = lane; e < E; e += 64) s += xr[e];
#pragma unroll
    for (int mm = 32; mm >= 1; mm >>= 1) s += __shfl_xor(s, mm, 64);
    float mean = s * invE;
    float v = 0.f;
    for (int e = lane; e < E; e += 64) { float d = xr[e] - mean; v += d * d; }
#pragma unroll
    for (int mm = 32; mm >= 1; mm >>= 1) v += __shfl_xor(v, mm, 64);
    float inv = rsqrtf(v * invE + 1e-5f);
    float* orow = xg + (size_t)row * E;
    for (int e = lane; e < E; e += 64) orow[e] = (xr[e] - mean) * inv * g[e] + b[e];
}

// ---------------------------------------------------------------------------
// Attention core: per 8-token group, scores -> softmax -> PV -> residual.
// qkv rows are chunk-local (img0 images offset). grid (Gg, nimg).
// ---------------------------------------------------------------------------
__global__ void attn_sm_k(const float* __restrict__ qkv, float* __restrict__ x,
                          int img0, int N, int E, int H, int HD, float rscale) {
    extern __shared__ float sc[];   // H*64 floats
    int g = blockIdx.x, im = blockIdx.y, t = threadIdx.x;
    int t0 = g * 8, nv = min(8, N - t0);
    int E3 = 3 * E;
    const float* qb = qkv + ((size_t)im * N + t0) * E3;
    float* xb = x + (((size_t)(img0 + im)) * N + t0) * E;
    // scores
    for (int idx = t; idx < H * 64; idx += 256) {
        int h = idx >> 6, qr = (idx >> 3) & 7, kr = idx & 7;
        float s = 0.f;
        if (qr < nv && kr < nv) {
            const float* qp = qb + (size_t)qr * E3 + h * HD;
            const float* kp = qb + (size_t)kr * E3 + E + h * HD;
            for (int d = 0; d < HD; ++d) s += qp[d] * kp[d];
        }
        sc[idx] = s * rscale;
    }
    __syncthreads();
    // softmax per (h, qr)
    for (int idx = t; idx < H * 8; idx += 256) {
        int h = idx >> 3, qr = idx & 7;
        if (qr < nv) {
            float* row = sc + h * 64 + qr * 8;
            float mx = -1e30f;
            for (int k = 0; k < nv; ++k) mx = fmaxf(mx, row[k]);
            float sum = 0.f;
            for (int k = 0; k < nv; ++k) { float e = expf(row[k] - mx); row[k] = e; sum += e; }
            float inv = 1.f / sum;
            for (int k = 0; k < nv; ++k) row[k] *= inv;
        }
    }
    __syncthreads();
    // PV + residual
    for (int c = t; c < E; c += 256) {
        int h = c / HD;
        const float* srow = sc + h * 64;
        for (int r = 0; r < nv; ++r) {
            float o = 0.f;
            for (int k = 0; k < nv; ++k)
                o += srow[r * 8 + k] * qb[(size_t)k * E3 + 2 * E + c];
            xb[(size_t)r * E + c] += o;
        }
    }
}

// ---------------------------------------------------------------------------
// Head: x[:,0] @ fc_w + fc_b
// ---------------------------------------------------------------------------
__global__ void head_k(const float* __restrict__ fw, const float* __restrict__ fb,
                       const float* __restrict__ x, float* __restrict__ out,
                       int Bc, int N, int E, int NC) {
    int idx = blockIdx.x * 256 + threadIdx.x;
    if (idx < Bc * NC) {
        int b = idx / NC, nc = idx % NC;
        float acc = fb[nc];
        const float* xr = x + (size_t)b * N * E;
        for (int e = 0; e < E; ++e) acc += xr[e] * fw[(size_t)e * NC + nc];
        out[idx] = acc;
    }
}

// ---------------------------------------------------------------------------
static int isqrt_i(long long v) {
    if (v < 0) return -1;
    long long r = (long long)(sqrt((double)v) + 0.5);
    while (r * r > v) --r;
    while ((r + 1) * (r + 1) <= v) ++r;
    return (int)r;
}

extern "C" void kernel_launch(void* const* d_in, const int* in_sizes, int n_in,
                              void* d_out, int out_size, void* d_ws, size_t ws_size,
                              hipStream_t stream) {
    float* out = (float*)d_out;
    int nblk_out = (out_size + 255) / 256;
#define DUMP(code, val) do { \
        dump_k<<<nblk_out, 256, 0, stream>>>(out, out_size, (float)((code) * 1000000.0 + (double)(val))); \
        return; } while (0)

    if (n_in != 22) DUMP(1, n_in < 999999 ? n_in : 999999);
    const int* S = in_sizes;

    int E = S[2];
    if (E <= 0 || S[4] != E) DUMP(2, 4);
    if (S[6] % E) DUMP(2, 6);
    int L = S[6] / E;
    if (L <= 0) DUMP(2, 6);
    long long EE = (long long)E * E;
    if (S[5] != L * EE || S[7] != L * EE || S[9] != L * EE) DUMP(2, 5);
    if (S[8] != L * E || S[10] != L * E) DUMP(2, 8);
    if (S[12] != L * E || S[13] != L * E || S[14] != L * E || S[15] != L * E) DUMP(2, 12);
    if (S[19] != L * E) DUMP(2, 19);
    if (S[11] % L) DUMP(2, 11);
    int HD = isqrt_i(S[11] / L);
    if ((long long)HD * HD * L != S[11] || HD <= 0 || E % HD) DUMP(3, HD > 0 ? HD : 0);
    int H = E / HD;
    if (S[17] % L) DUMP(2, 17);
    int FF = S[17] / L;
    if (S[16] != (long long)L * E * FF) DUMP(2, 16);
    if (S[18] != (long long)L * FF * E) DUMP(2, 18);
    if (S[3] % E) DUMP(2, 3);
    int N = S[3] / E;
    int m = isqrt_i(N - 1);
    if (m <= 0 || m * m != N - 1) DUMP(4, N < 999999 ? N : 999999);
    int NC = S[21];
    if (NC <= 0 || S[20] != (long long)E * NC) DUMP(2, 20);
    if (out_size % NC) DUMP(8, out_size < 999999 ? out_size : 999999);
    int Bc = out_size / NC;
    if (S[1] % E) DUMP(2, 1);
    int K = S[1] / E;
    static const int corder[12] = {3, 4, 1, 2, 8, 16, 6, 12, 32, 64, 24, 48};
    int C = -1, P = -1;
    for (int ci = 0; ci < 12; ++ci) {
        int c = corder[ci];
        if (K % c) continue;
        int p = isqrt_i(K / c);
        if (p > 0 && p * p * c == K) {
            long long img = (long long)p * m;
            if ((long long)Bc * c * img * img == S[0]) { C = c; P = p; break; }
        }
    }
    if (C < 0) DUMP(5, K < 999999 ? K : 999999);
    int IMG = P * m;
    int TOK = Bc * N;
    int Gg = (N + 7) / 8;
    int E3 = 3 * E;

    // workspace layout (f32): x[TOK*E] | xg[TOK*E] | Wqkv[E*3E] | bqkv[3E] | buf
    size_t off_x = 0;
    size_t off_xg = off_x + (size_t)TOK * E;
    size_t off_wq = off_xg + (size_t)TOK * E;
    size_t off_bq = off_wq + (size_t)E * E3;
    size_t off_buf = off_bq + (size_t)E3;
    size_t total_f = ws_size / 4;
    if (off_buf >= total_f) DUMP(6, (double)(ws_size >> 20));
    size_t buf_f = total_f - off_buf;
    long long rowNE3 = (long long)N * E3;
    int CHI = (int)(buf_f / rowNE3);
    if (CHI > Bc) CHI = Bc;
    long long chf_l = (long long)(buf_f / FF);
    chf_l = (chf_l / 64) * 64;
    int CHF = chf_l > TOK ? TOK : (int)chf_l;
    if (CHI < 1 || CHF < 64) DUMP(6, (double)(ws_size >> 20));

    float* ws = (float*)d_ws;
    float* x    = ws + off_x;
    float* xg   = ws + off_xg;
    float* Wqkv = ws + off_wq;
    float* bqkv = ws + off_bq;
    float* buf  = ws + off_buf;

    const float* src = (const float*)d_in[0];
    const float* cw  = (const float*)d_in[1];
    const float* cb  = (const float*)d_in[2];
    const float* pos = (const float*)d_in[3];
    const float* cls = (const float*)d_in[4];
    const float* Wq  = (const float*)d_in[5];
    const float* bq  = (const float*)d_in[6];
    const float* Wk  = (const float*)d_in[7];
    const float* bk  = (const float*)d_in[8];
    const float* Wv  = (const float*)d_in[9];
    const float* bv  = (const float*)d_in[10];
    const float* fp  = (const float*)d_in[11];
    const float* g1  = (const float*)d_in[12];
    const float* b1  = (const float*)d_in[13];
    const float* g2  = (const float*)d_in[14];
    const float* b2  = (const float*)d_in[15];
    const float* w1  = (const float*)d_in[16];
    const float* bb1 = (const float*)d_in[17];
    const float* w2  = (const float*)d_in[18];
    const float* bb2 = (const float*)d_in[19];
    const float* fcw = (const float*)d_in[20];
    const float* fcb = (const float*)d_in[21];

    float invE = 1.f / (float)E;
    float rscale = 1.f / sqrtf((float)HD);

    // ---- embed
    size_t patch_sh = (size_t)K * sizeof(float);
    if (patch_sh <= 48000)
        embed_lds_k<<<dim3(N, Bc), 256, patch_sh, stream>>>(src, cw, cb, pos, cls, x,
                                                            C, IMG, P, m, E, N, K);
    else
        embed_dir_k<<<dim3(N, Bc), 256, 0, stream>>>(src, cw, cb, pos, cls, x,
                                                     C, IMG, P, m, E, N, K);

    int ln_grid = (TOK + 3) / 4;
    int gmE = (E + BM - 1) / BM;           // row tiles for M=E
    int gnHD = (HD + BN - 1) / BN;         // col tiles for N=HD
    size_t attn_sh = (size_t)H * 64 * sizeof(float);

    for (int l = 0; l < L; ++l) {
        const float* Wq_l = Wq + (size_t)l * EE;
        const float* Wk_l = Wk + (size_t)l * EE;
        const float* Wv_l = Wv + (size_t)l * EE;
        const float* fp_l = fp + (size_t)l * HD * HD;

        // ---- fold fproj into Wq/Wk (per head GEMMs), copy V, fold biases
        for (int h = 0; h < H; ++h) {
            gemm_k<<<dim3(gmE, gnHD), 256, 0, stream>>>(
                Wq_l + (size_t)h * HD, E, fp_l, HD,
                Wqkv + (size_t)h * HD, E3, nullptr, E, HD, HD, 0);
            gemm_k<<<dim3(gmE, gnHD), 256, 0, stream>>>(
                Wk_l + (size_t)h * HD, E, fp_l, HD,
                Wqkv + (size_t)(E + h * HD), E3, nullptr, E, HD, HD, 0);
        }
        copyv_k<<<(int)((EE + 255) / 256), 256, 0, stream>>>(Wv_l, Wqkv, E);
        biasfold_k<<<(E3 + 255) / 256, 256, 0, stream>>>(
            bq + (size_t)l * E, bk + (size_t)l * E, bv + (size_t)l * E,
            fp_l, bqkv, E, HD);

        // ---- LN1
        ln_k<<<ln_grid, 256, 0, stream>>>(x, g1 + (size_t)l * E, b1 + (size_t)l * E,
                                          xg, TOK, E, invE);
        // ---- QKV GEMM + attention core, chunked by images
        for (int img0 = 0; img0 < Bc; img0 += CHI) {
            int nimg = Bc - img0 < CHI ? Bc - img0 : CHI;
            int ntok = nimg * N;
            gemm_k<<<dim3((ntok + BM - 1) / BM, (E3 + BN - 1) / BN), 256, 0, stream>>>(
                xg + (size_t)img0 * N * E, E, Wqkv, E3, buf, E3, bqkv,
                ntok, E3, E, 0);
            attn_sm_k<<<dim3(Gg, nimg), 256, attn_sh, stream>>>(
                buf, x, img0, N, E, H, HD, rscale);
        }
        // ---- LN2 + FFN, chunked by rows
        ln_k<<<ln_grid, 256, 0, stream>>>(x, g2 + (size_t)l * E, b2 + (size_t)l * E,
                                          xg, TOK, E, invE);
        for (int tok0 = 0; tok0 < TOK; tok0 += CHF) {
            int ntok = TOK - tok0 < CHF ? TOK - tok0 : CHF;
            int gx = (ntok + BM - 1) / BM;
            gemm_k<<<dim3(gx, (FF + BN - 1) / BN), 256, 0, stream>>>(
                xg + (size_t)tok0 * E, E, w1 + (size_t)l * E * FF, FF,
                buf, FF, bb1 + (size_t)l * FF, ntok, FF, E, 1);
            gemm_k<<<dim3(gx, (E + BN - 1) / BN), 256, 0, stream>>>(
                buf, FF, w2 + (size_t)l * FF * E, E,
                x + (size_t)tok0 * E, E, bb2 + (size_t)l * E, ntok, E, FF, 2);
        }
    }
    head_k<<<nblk_out, 256, 0, stream>>>(fcw, fcb, x, out, Bc, N, E, NC);
#undef DUMP
}

// Round 7
// 25249.706 us; speedup vs baseline: 4.6373x; 1.0608x over previous
//
#include <hip/hip_runtime.h>
#include <math.h>

typedef __attribute__((ext_vector_type(8))) short short8v;
typedef __attribute__((ext_vector_type(4))) float float4v;

__device__ __forceinline__ float gelu_f(float v) {
    return 0.5f * v * (1.0f + erff(v * 0.70710678118654752440f));
}

__device__ __forceinline__ unsigned short bf16r(float f) {
    unsigned u = __float_as_uint(f);
    u += 0x7FFFu + ((u >> 16) & 1u);
    return (unsigned short)(u >> 16);
}

__device__ __forceinline__ float bf2f(unsigned short s) {
    unsigned u = ((unsigned)s) << 16;
    return __uint_as_float(u);
}

// ---------------------------------------------------------------------------
// Diagnostic dump
// ---------------------------------------------------------------------------
__global__ void dump_k(float* __restrict__ out, int n, float val) {
    int t = blockIdx.x * 256 + threadIdx.x;
    if (t < n) out[t] = val;
}

// ---------------------------------------------------------------------------
// Flat convert f32 -> bf16
// ---------------------------------------------------------------------------
__global__ void ck_k(const float* __restrict__ in, unsigned short* __restrict__ out,
                     long long n) {
    long long i = (long long)blockIdx.x * 256 + threadIdx.x;
    if (i < n) out[i] = bf16r(in[i]);
}

// ---------------------------------------------------------------------------
// Transpose-convert: in[R][Cc] f32 -> out[Cc][R] bf16. 32x32 LDS tiles.
// ---------------------------------------------------------------------------
__global__ void tc_k(const float* __restrict__ in, unsigned short* __restrict__ out,
                     int R, int Cc) {
    __shared__ float tile[32][33];
    int t = threadIdx.x;
    int tx = t & 31, ty = t >> 5;       // 32 x 8
    int r0 = blockIdx.x * 32, c0 = blockIdx.y * 32;
#pragma unroll
    for (int i = 0; i < 4; ++i) {
        int r = r0 + ty + i * 8, c = c0 + tx;
        tile[ty + i * 8][tx] = (r < R && c < Cc) ? in[(size_t)r * Cc + c] : 0.f;
    }
    __syncthreads();
#pragma unroll
    for (int i = 0; i < 4; ++i) {
        int c = c0 + ty + i * 8, r = r0 + tx;
        if (c < Cc && r < R) out[(size_t)c * R + r] = bf16r(tile[tx][ty + i * 8]);
    }
}

// ---------------------------------------------------------------------------
// bf16 MFMA GEMM v2: C[M,N] = op(A[M,K] @ Bt[N,K]^T + bias)
// A, Bt bf16 row-major. Tile 128x128x64, 512 threads, 8 waves (2M x 4N).
// LDS chunk-XOR swizzle (chunk ^= row&7) on 16B units -> conflict-free b128.
// op: 0 = f32 store, 1 = gelu -> bf16 store, 2 = f32 add (residual), 3 = bf16 store
// al: 1 if 16B-aligned fast staging is safe (lda/ldbt/base all %8 == 0).
// ---------------------------------------------------------------------------
__global__ __launch_bounds__(512) void gemm2_k(
        const unsigned short* __restrict__ A, int lda,
        const unsigned short* __restrict__ Bt, int ldbt,
        void* __restrict__ Cv, int ldc,
        const float* __restrict__ bias,
        int M, int Nn, int K, int op, int al) {
    __shared__ unsigned short Ab[128 * 64];
    __shared__ unsigned short Bb[128 * 64];
    int t = threadIdx.x;
    int m0 = blockIdx.x * 128, n0 = blockIdx.y * 128;
    int w = t >> 6, lane = t & 63;
    int wm = w >> 2, wn = w & 3;        // 2 x 4 wave grid
    int lrow = lane & 15, lk = lane >> 4;

    float4v acc[4][2];
#pragma unroll
    for (int fa = 0; fa < 4; ++fa)
#pragma unroll
        for (int fb = 0; fb < 2; ++fb) acc[fa][fb] = (float4v){0.f, 0.f, 0.f, 0.f};

    for (int k0 = 0; k0 < K; k0 += 64) {
        __syncthreads();
        // ---- stage A: 128 rows x 8 chunks of 8 bf16
#pragma unroll
        for (int cc = 0; cc < 2; ++cc) {
            int c = t + cc * 512;
            int row = c >> 3, ch = c & 7;
            int gm = m0 + row, gk = k0 + ch * 8;
            short8v v = {0, 0, 0, 0, 0, 0, 0, 0};
            if (gm < M) {
                if (al && gk + 8 <= K) {
                    v = *(const short8v*)(A + (size_t)gm * lda + gk);
                } else {
                    const unsigned short* p = A + (size_t)gm * lda;
#pragma unroll
                    for (int j = 0; j < 8; ++j)
                        if (gk + j < K) v[j] = (short)p[gk + j];
                }
            }
            *(short8v*)&Ab[row * 64 + ((ch ^ (row & 7)) << 3)] = v;
        }
        // ---- stage Bt: 128 n-rows x 8 chunks
#pragma unroll
        for (int cc = 0; cc < 2; ++cc) {
            int c = t + cc * 512;
            int row = c >> 3, ch = c & 7;
            int gn = n0 + row, gk = k0 + ch * 8;
            short8v v = {0, 0, 0, 0, 0, 0, 0, 0};
            if (gn < Nn) {
                if (al && gk + 8 <= K) {
                    v = *(const short8v*)(Bt + (size_t)gn * ldbt + gk);
                } else {
                    const unsigned short* p = Bt + (size_t)gn * ldbt;
#pragma unroll
                    for (int j = 0; j < 8; ++j)
                        if (gk + j < K) v[j] = (short)p[gk + j];
                }
            }
            *(short8v*)&Bb[row * 64 + ((ch ^ (row & 7)) << 3)] = v;
        }
        __syncthreads();
        // ---- MFMA: 2 k-steps of 32
#pragma unroll
        for (int ks = 0; ks < 2; ++ks) {
            short8v af[4], bf[2];
#pragma unroll
            for (int fa = 0; fa < 4; ++fa) {
                int row = wm * 64 + fa * 16 + lrow;
                af[fa] = *(const short8v*)&Ab[row * 64 + (((ks * 4 + lk) ^ (row & 7)) << 3)];
            }
#pragma unroll
            for (int fb = 0; fb < 2; ++fb) {
                int row = wn * 32 + fb * 16 + lrow;
                bf[fb] = *(const short8v*)&Bb[row * 64 + (((ks * 4 + lk) ^ (row & 7)) << 3)];
            }
#pragma unroll
            for (int fa = 0; fa < 4; ++fa)
#pragma unroll
                for (int fb = 0; fb < 2; ++fb)
                    acc[fa][fb] = __builtin_amdgcn_mfma_f32_16x16x32_bf16(
                        af[fa], bf[fb], acc[fa][fb], 0, 0, 0);
        }
    }
    // ---- epilogue: D[row][col], col = lane&15 side (B), row = (lane>>4)*4+q (A)
    float* Cf = (float*)Cv;
    unsigned short* Cu = (unsigned short*)Cv;
#pragma unroll
    for (int fb = 0; fb < 2; ++fb) {
        int col = n0 + wn * 32 + fb * 16 + lrow;
        if (col >= Nn) continue;
        float bb = bias ? bias[col] : 0.f;
#pragma unroll
        for (int fa = 0; fa < 4; ++fa) {
#pragma unroll
            for (int q = 0; q < 4; ++q) {
                int row = m0 + wm * 64 + fa * 16 + lk * 4 + q;
                if (row >= M) continue;
                float v = acc[fa][fb][q] + bb;
                size_t idx = (size_t)row * ldc + col;
                if (op == 0) Cf[idx] = v;
                else if (op == 1) Cu[idx] = bf16r(gelu_f(v));
                else if (op == 2) Cf[idx] += v;
                else Cu[idx] = bf16r(v);
            }
        }
    }
}

// ---------------------------------------------------------------------------
// Fold biases: bqkv[0:E]=bq@fp per head, [E:2E]=bk@fp, [2E:3E]=bv  (f32)
// ---------------------------------------------------------------------------
__global__ void biasfold_k(const float* __restrict__ bq, const float* __restrict__ bk,
                           const float* __restrict__ bv, const float* __restrict__ fp,
                           float* __restrict__ bqkv, int E, int HD) {
    int c = blockIdx.x * 256 + threadIdx.x;
    if (c >= 3 * E) return;
    if (c < 2 * E) {
        int mat = c / E, cc = c % E, h = cc / HD, j = cc % HD;
        const float* bb = mat ? bk : bq;
        float s = 0.f;
        for (int d = 0; d < HD; ++d) s += bb[h * HD + d] * fp[(size_t)d * HD + j];
        bqkv[c] = s;
    } else {
        bqkv[c] = bv[c - 2 * E];
    }
}

// ---------------------------------------------------------------------------
// Patch embed + cls + pos -> x f32. grid (N, B), block 256.
// ---------------------------------------------------------------------------
__global__ void embed_lds_k(const float* __restrict__ src, const float* __restrict__ cw,
                            const float* __restrict__ cb, const float* __restrict__ pos,
                            const float* __restrict__ cls, float* __restrict__ x,
                            int C, int IMG, int P, int m, int E, int N, int K) {
    extern __shared__ float patch[];
    int n = blockIdx.x, b = blockIdx.y, t = threadIdx.x;
    if (n == 0) {
        for (int e = t; e < E; e += 256)
            x[((size_t)b * N) * E + e] = cls[e] + pos[e];
        return;
    }
    int p = n - 1, ph = p / m, pw = p % m;
    int P2 = P * P;
    for (int mm = t; mm < K; mm += 256) {
        int c = mm / P2, rem = mm % P2, i = rem / P, j = rem % P;
        patch[mm] = src[(((size_t)b * C + c) * IMG + ph * P + i) * IMG + pw * P + j];
    }
    __syncthreads();
    for (int e = t; e < E; e += 256) {
        float acc = cb[e];
        const float* wr = cw + (size_t)e * K;
        for (int mm = 0; mm < K; ++mm) acc += patch[mm] * wr[mm];
        x[((size_t)b * N + n) * E + e] = acc + pos[(size_t)n * E + e];
    }
}

__global__ void embed_dir_k(const float* __restrict__ src, const float* __restrict__ cw,
                            const float* __restrict__ cb, const float* __restrict__ pos,
                            const float* __restrict__ cls, float* __restrict__ x,
                            int C, int IMG, int P, int m, int E, int N, int K) {
    int n = blockIdx.x, b = blockIdx.y, t = threadIdx.x;
    if (n == 0) {
        for (int e = t; e < E; e += 256)
            x[((size_t)b * N) * E + e] = cls[e] + pos[e];
        return;
    }
    int p = n - 1, ph = p / m, pw = p % m;
    int P2 = P * P;
    for (int e = t; e < E; e += 256) {
        float acc = cb[e];
        const float* wr = cw + (size_t)e * K;
        for (int mm = 0; mm < K; ++mm) {
            int c = mm / P2, rem = mm % P2, i = rem / P, j = rem % P;
            acc += src[(((size_t)b * C + c) * IMG + ph * P + i) * IMG + pw * P + j] * wr[mm];
        }
        x[((size_t)b * N + n) * E + e] = acc + pos[(size_t)n * E + e];
    }
}

// ---------------------------------------------------------------------------
// LayerNorm rows of x f32 -> xg bf16. grid ceil(TOK/4), block 256.
// ---------------------------------------------------------------------------
__global__ void ln_k(const float* __restrict__ x, const float* __restrict__ g,
                     const float* __restrict__ b, unsigned short* __restrict__ xg,
                     int TOK, int E, float invE) {
    int row = blockIdx.x * 4 + (threadIdx.x >> 6);
    int lane = threadIdx.x & 63;
    if (row >= TOK) return;
    const float* xr = x + (size_t)row * E;
    float s = 0.f;
    for (int e = lane; e < E; e += 64) s += xr[e];
#pragma unroll
    for (int mm = 32; mm >= 1; mm >>= 1) s += __shfl_xor(s, mm, 64);
    float mean = s * invE;
    float v = 0.f;
    for (int e = lane; e < E; e += 64) { float d = xr[e] - mean; v += d * d; }
#pragma unroll
    for (int mm = 32; mm >= 1; mm >>= 1) v += __shfl_xor(v, mm, 64);
    float inv = rsqrtf(v * invE + 1e-5f);
    unsigned short* orow = xg + (size_t)row * E;
    for (int e = lane; e < E; e += 64)
        orow[e] = bf16r((xr[e] - mean) * inv * g[e] + b[e]);
}

// ---------------------------------------------------------------------------
// Attention core: per 8-token group, scores -> softmax -> PV -> residual.
// qkv f32 chunk-local. grid (Gg, nimg).
// ---------------------------------------------------------------------------
__global__ void attn_sm_k(const float* __restrict__ qkv, float* __restrict__ x,
                          int img0, int N, int E, int H, int HD, float rscale) {
    extern __shared__ float sc[];   // H*64
    int g = blockIdx.x, im = blockIdx.y, t = threadIdx.x;
    int t0 = g * 8, nv = min(8, N - t0);
    int E3 = 3 * E;
    const float* qb = qkv + ((size_t)im * N + t0) * E3;
    float* xb = x + (((size_t)(img0 + im)) * N + t0) * E;
    for (int idx = t; idx < H * 64; idx += 256) {
        int h = idx >> 6, qr = (idx >> 3) & 7, kr = idx & 7;
        float s = 0.f;
        if (qr < nv && kr < nv) {
            const float* qp = qb + (size_t)qr * E3 + h * HD;
            const float* kp = qb + (size_t)kr * E3 + E + h * HD;
            for (int d = 0; d < HD; ++d) s += qp[d] * kp[d];
        }
        sc[idx] = s * rscale;
    }
    __syncthreads();
    for (int idx = t; idx < H * 8; idx += 256) {
        int h = idx >> 3, qr = idx & 7;
        if (qr < nv) {
            float* row = sc + h * 64 + qr * 8;
            float mx = -1e30f;
            for (int k = 0; k < nv; ++k) mx = fmaxf(mx, row[k]);
            float sum = 0.f;
            for (int k = 0; k < nv; ++k) { float e = expf(row[k] - mx); row[k] = e; sum += e; }
            float inv = 1.f / sum;
            for (int k = 0; k < nv; ++k) row[k] *= inv;
        }
    }
    __syncthreads();
    for (int c = t; c < E; c += 256) {
        int h = c / HD;
        const float* srow = sc + h * 64;
        for (int r = 0; r < nv; ++r) {
            float o = 0.f;
            for (int k = 0; k < nv; ++k)
                o += srow[r * 8 + k] * qb[(size_t)k * E3 + 2 * E + c];
            xb[(size_t)r * E + c] += o;
        }
    }
}

// ---------------------------------------------------------------------------
// Head: x[:,0] @ fc_w + fc_b
// ---------------------------------------------------------------------------
__global__ void head_k(const float* __restrict__ fw, const float* __restrict__ fb,
                       const float* __restrict__ x, float* __restrict__ out,
                       int Bc, int N, int E, int NC) {
    int idx = blockIdx.x * 256 + threadIdx.x;
    if (idx < Bc * NC) {
        int b = idx / NC, nc = idx % NC;
        float acc = fb[nc];
        const float* xr = x + (size_t)b * N * E;
        for (int e = 0; e < E; ++e) acc += xr[e] * fw[(size_t)e * NC + nc];
        out[idx] = acc;
    }
}

// ---------------------------------------------------------------------------
static int isqrt_i(long long v) {
    if (v < 0) return -1;
    long long r = (long long)(sqrt((double)v) + 0.5);
    while (r * r > v) --r;
    while ((r + 1) * (r + 1) <= v) ++r;
    return (int)r;
}

extern "C" void kernel_launch(void* const* d_in, const int* in_sizes, int n_in,
                              void* d_out, int out_size, void* d_ws, size_t ws_size,
                              hipStream_t stream) {
    float* out = (float*)d_out;
    int nblk_out = (out_size + 255) / 256;
#define DUMP(code, val) do { \
        dump_k<<<nblk_out, 256, 0, stream>>>(out, out_size, (float)((code) * 1000000.0 + (double)(val))); \
        return; } while (0)

    if (n_in != 22) DUMP(1, n_in < 999999 ? n_in : 999999);
    const int* S = in_sizes;

    int E = S[2];
    if (E <= 0 || S[4] != E) DUMP(2, 4);
    if (S[6] % E) DUMP(2, 6);
    int L = S[6] / E;
    if (L <= 0) DUMP(2, 6);
    long long EE = (long long)E * E;
    if (S[5] != L * EE || S[7] != L * EE || S[9] != L * EE) DUMP(2, 5);
    if (S[8] != L * E || S[10] != L * E) DUMP(2, 8);
    if (S[12] != L * E || S[13] != L * E || S[14] != L * E || S[15] != L * E) DUMP(2, 12);
    if (S[19] != L * E) DUMP(2, 19);
    if (S[11] % L) DUMP(2, 11);
    int HD = isqrt_i(S[11] / L);
    if ((long long)HD * HD * L != S[11] || HD <= 0 || E % HD) DUMP(3, HD > 0 ? HD : 0);
    int H = E / HD;
    if (S[17] % L) DUMP(2, 17);
    int FF = S[17] / L;
    if (S[16] != (long long)L * E * FF) DUMP(2, 16);
    if (S[18] != (long long)L * FF * E) DUMP(2, 18);
    if (S[3] % E) DUMP(2, 3);
    int N = S[3] / E;
    int m = isqrt_i(N - 1);
    if (m <= 0 || m * m != N - 1) DUMP(4, N < 999999 ? N : 999999);
    int NC = S[21];
    if (NC <= 0 || S[20] != (long long)E * NC) DUMP(2, 20);
    if (out_size % NC) DUMP(8, out_size < 999999 ? out_size : 999999);
    int Bc = out_size / NC;
    if (S[1] % E) DUMP(2, 1);
    int K = S[1] / E;
    static const int corder[12] = {3, 4, 1, 2, 8, 16, 6, 12, 32, 64, 24, 48};
    int C = -1, P = -1;
    for (int ci = 0; ci < 12; ++ci) {
        int c = corder[ci];
        if (K % c) continue;
        int p = isqrt_i(K / c);
        if (p > 0 && p * p * c == K) {
            long long img = (long long)p * m;
            if ((long long)Bc * c * img * img == S[0]) { C = c; P = p; break; }
        }
    }
    if (C < 0) DUMP(5, K < 999999 ? K : 999999);
    int IMG = P * m;
    int TOK = Bc * N;
    int Gg = (N + 7) / 8;
    int E3 = 3 * E;
    int al = ((E % 8) == 0 && (HD % 8) == 0 && (FF % 8) == 0) ? 1 : 0;

    // ---- workspace layout (byte offsets, 256-aligned)
    size_t off = 0;
    auto alloc = [&](size_t bytes) { size_t o = off; off = (off + bytes + 255) & ~(size_t)255; return o; };
    size_t o_x    = alloc((size_t)TOK * E * 4);        // x f32
    size_t o_xg   = alloc((size_t)TOK * E * 2);        // xg bf16
    size_t o_wqkv = alloc((size_t)E3 * E * 2);         // Wqkv_t bf16 [3E][E]
    size_t o_w1t  = alloc((size_t)E * FF * 2);         // w1t bf16 [FF][E]
    size_t o_w2t  = alloc((size_t)E * FF * 2);         // w2t bf16 [E][FF]
    size_t o_wtmp = alloc(EE * 2);                     // Wq/Wk bf16 tmp
    size_t o_fpt  = alloc((size_t)HD * HD * 2);        // fpT bf16
    size_t o_bqkv = alloc((size_t)E3 * 4);             // bqkv f32
    size_t o_buf  = off;
    if (o_buf >= ws_size) DUMP(6, (double)(ws_size >> 20));
    size_t buf_bytes = ws_size - o_buf;
    // chunk sizes
    long long qkv_img_bytes = (long long)N * E3 * 4;
    int CHI = (int)(buf_bytes / qkv_img_bytes);
    if (CHI > Bc) CHI = Bc;
    long long chf_l = (long long)(buf_bytes / ((long long)FF * 2));
    chf_l = (chf_l / 128) * 128;
    int CHF = chf_l > TOK ? TOK : (int)chf_l;
    if (CHI < 1 || CHF < 128) DUMP(6, (double)(ws_size >> 20));

    char* wsb = (char*)d_ws;
    float* x            = (float*)(wsb + o_x);
    unsigned short* xg  = (unsigned short*)(wsb + o_xg);
    unsigned short* Wqkv_t = (unsigned short*)(wsb + o_wqkv);
    unsigned short* w1t = (unsigned short*)(wsb + o_w1t);
    unsigned short* w2t = (unsigned short*)(wsb + o_w2t);
    unsigned short* Wtmp = (unsigned short*)(wsb + o_wtmp);
    unsigned short* fpT = (unsigned short*)(wsb + o_fpt);
    float* bqkv         = (float*)(wsb + o_bqkv);
    float* buff         = (float*)(wsb + o_buf);
    unsigned short* bufh = (unsigned short*)(wsb + o_buf);

    const float* src = (const float*)d_in[0];
    const float* cw  = (const float*)d_in[1];
    const float* cb  = (const float*)d_in[2];
    const float* pos = (const float*)d_in[3];
    const float* cls = (const float*)d_in[4];
    const float* Wq  = (const float*)d_in[5];
    const float* bq  = (const float*)d_in[6];
    const float* Wk  = (const float*)d_in[7];
    const float* bk  = (const float*)d_in[8];
    const float* Wv  = (const float*)d_in[9];
    const float* bv  = (const float*)d_in[10];
    const float* fp  = (const float*)d_in[11];
    const float* g1  = (const float*)d_in[12];
    const float* b1  = (const float*)d_in[13];
    const float* g2  = (const float*)d_in[14];
    const float* b2  = (const float*)d_in[15];
    const float* w1  = (const float*)d_in[16];
    const float* bb1 = (const float*)d_in[17];
    const float* w2  = (const float*)d_in[18];
    const float* bb2 = (const float*)d_in[19];
    const float* fcw = (const float*)d_in[20];
    const float* fcb = (const float*)d_in[21];

    float invE = 1.f / (float)E;
    float rscale = 1.f / sqrtf((float)HD);

    // ---- embed
    size_t patch_sh = (size_t)K * sizeof(float);
    if (patch_sh <= 48000)
        embed_lds_k<<<dim3(N, Bc), 256, patch_sh, stream>>>(src, cw, cb, pos, cls, x,
                                                            C, IMG, P, m, E, N, K);
    else
        embed_dir_k<<<dim3(N, Bc), 256, 0, stream>>>(src, cw, cb, pos, cls, x,
                                                     C, IMG, P, m, E, N, K);

    int ln_grid = (TOK + 3) / 4;
    size_t attn_sh = (size_t)H * 64 * sizeof(float);
    int tcg = 256;   // threads for tc/ck
    dim3 gFoldQ((HD + 127) / 128, (E + 127) / 128);

    for (int l = 0; l < L; ++l) {
        const float* Wq_l = Wq + (size_t)l * EE;
        const float* Wk_l = Wk + (size_t)l * EE;
        const float* Wv_l = Wv + (size_t)l * EE;
        const float* fp_l = fp + (size_t)l * HD * HD;

        // ---- per-layer weight prep (bf16)
        tc_k<<<dim3((HD + 31) / 32, (HD + 31) / 32), tcg, 0, stream>>>(fp_l, fpT, HD, HD);
        ck_k<<<(int)((EE + 255) / 256), tcg, 0, stream>>>(Wq_l, Wtmp, EE);
        for (int h = 0; h < H; ++h)
            gemm2_k<<<gFoldQ, 512, 0, stream>>>(
                fpT, HD, Wtmp + h * HD, E, Wqkv_t + (size_t)(h * HD) * E, E,
                nullptr, HD, E, HD, 3, al);
        ck_k<<<(int)((EE + 255) / 256), tcg, 0, stream>>>(Wk_l, Wtmp, EE);
        for (int h = 0; h < H; ++h)
            gemm2_k<<<gFoldQ, 512, 0, stream>>>(
                fpT, HD, Wtmp + h * HD, E, Wqkv_t + (size_t)(E + h * HD) * E, E,
                nullptr, HD, E, HD, 3, al);
        tc_k<<<dim3((E + 31) / 32, (E + 31) / 32), tcg, 0, stream>>>(
            Wv_l, Wqkv_t + (size_t)(2 * E) * E, E, E);
        biasfold_k<<<(E3 + 255) / 256, tcg, 0, stream>>>(
            bq + (size_t)l * E, bk + (size_t)l * E, bv + (size_t)l * E, fp_l, bqkv, E, HD);
        tc_k<<<dim3((E + 31) / 32, (FF + 31) / 32), tcg, 0, stream>>>(
            w1 + (size_t)l * E * FF, w1t, E, FF);
        tc_k<<<dim3((FF + 31) / 32, (E + 31) / 32), tcg, 0, stream>>>(
            w2 + (size_t)l * FF * E, w2t, FF, E);

        // ---- LN1 -> xg bf16
        ln_k<<<ln_grid, 256, 0, stream>>>(x, g1 + (size_t)l * E, b1 + (size_t)l * E,
                                          xg, TOK, E, invE);
        // ---- QKV GEMM + attention, chunked by images
        for (int img0 = 0; img0 < Bc; img0 += CHI) {
            int nimg = Bc - img0 < CHI ? Bc - img0 : CHI;
            int ntok = nimg * N;
            gemm2_k<<<dim3((ntok + 127) / 128, (E3 + 127) / 128), 512, 0, stream>>>(
                xg + (size_t)img0 * N * E, E, Wqkv_t, E, buff, E3, bqkv,
                ntok, E3, E, 0, al);
            attn_sm_k<<<dim3(Gg, nimg), 256, attn_sh, stream>>>(
                buff, x, img0, N, E, H, HD, rscale);
        }
        // ---- LN2 -> xg bf16, FFN chunked by rows
        ln_k<<<ln_grid, 256, 0, stream>>>(x, g2 + (size_t)l * E, b2 + (size_t)l * E,
                                          xg, TOK, E, invE);
        for (int tok0 = 0; tok0 < TOK; tok0 += CHF) {
            int ntok = TOK - tok0 < CHF ? TOK - tok0 : CHF;
            int gx = (ntok + 127) / 128;
            gemm2_k<<<dim3(gx, (FF + 127) / 128), 512, 0, stream>>>(
                xg + (size_t)tok0 * E, E, w1t, E, bufh, FF,
                bb1 + (size_t)l * FF, ntok, FF, E, 1, al);
            gemm2_k<<<dim3(gx, (E + 127) / 128), 512, 0, stream>>>(
                bufh, FF, w2t, FF, x + (size_t)tok0 * E, E,
                bb2 + (size_t)l * E, ntok, E, FF, 2, al);
        }
    }
    head_k<<<nblk_out, 256, 0, stream>>>(fcw, fcb, x, out, Bc, N, E, NC);
#undef DUMP
}

// Round 8
// 10210.436 us; speedup vs baseline: 11.4676x; 2.4729x over previous
//
#include <hip/hip_runtime.h>
#include <math.h>

typedef __attribute__((ext_vector_type(8))) short short8v;
typedef __attribute__((ext_vector_type(4))) float float4v;

#if defined(__has_builtin)
#if __has_builtin(__builtin_amdgcn_global_load_lds)
#define USE_GLL 1
#endif
#endif
#ifndef USE_GLL
#define USE_GLL 0
#endif

__device__ __forceinline__ float gelu_f(float v) {
    return 0.5f * v * (1.0f + erff(v * 0.70710678118654752440f));
}

__device__ __forceinline__ unsigned short bf16r(float f) {
    unsigned u = __float_as_uint(f);
    u += 0x7FFFu + ((u >> 16) & 1u);
    return (unsigned short)(u >> 16);
}

__device__ __forceinline__ float bf2f(unsigned short s) {
    return __uint_as_float(((unsigned)s) << 16);
}

// ---------------------------------------------------------------------------
__global__ void dump_k(float* __restrict__ out, int n, float val) {
    int t = blockIdx.x * 256 + threadIdx.x;
    if (t < n) out[t] = val;
}

// ---------------------------------------------------------------------------
// Batched transpose-convert: in[R][Cc] f32 -> out[Cc][R] bf16; grid.z = layers.
// ---------------------------------------------------------------------------
__global__ void tc_k(const float* __restrict__ in0, unsigned short* __restrict__ out0,
                     int R, int Cc, long long ils, long long ols) {
    __shared__ float tile[32][33];
    int l = blockIdx.z;
    const float* in = in0 + (size_t)l * ils;
    unsigned short* out = out0 + (size_t)l * ols;
    int t = threadIdx.x;
    int tx = t & 31, ty = t >> 5;
    int r0 = blockIdx.x * 32, c0 = blockIdx.y * 32;
#pragma unroll
    for (int i = 0; i < 4; ++i) {
        int r = r0 + ty + i * 8, c = c0 + tx;
        tile[ty + i * 8][tx] = (r < R && c < Cc) ? in[(size_t)r * Cc + c] : 0.f;
    }
    __syncthreads();
#pragma unroll
    for (int i = 0; i < 4; ++i) {
        int c = c0 + ty + i * 8, r = r0 + tx;
        if (c < Cc && r < R) out[(size_t)c * R + r] = bf16r(tile[tx][ty + i * 8]);
    }
}

// ---------------------------------------------------------------------------
// Batched fproj fold: Wt rows n in [0,2E): n = s*E + h*HD + i
//   Wt[n][c] = sum_d Wsrc_s[c][h*HD+d] * fp[d][i],  Wsrc_0=Wq, Wsrc_1=Wk.
// grid ((2E+63)/64, 1, layers), block 256 = 64 n x 4 c-groups.
// mode: 0 = fpS[d][i] full (HD<=64), 1 = 64-wide window, 2 = direct global.
// ---------------------------------------------------------------------------
__global__ void fold_k(const float* __restrict__ Wq0, const float* __restrict__ Wk0,
                       const float* __restrict__ fp0, unsigned short* __restrict__ Wt0,
                       int E, int HD, int mode) {
    extern __shared__ float fpS[];
    int l = blockIdx.z;
    long long EE = (long long)E * E;
    const float* fp = fp0 + (size_t)l * HD * HD;
    unsigned short* Wt = Wt0 + (size_t)l * 3 * EE;
    int t = threadIdx.x;
    int n0 = blockIdx.x * 64;
    int n = n0 + (t & 63);
    int cg = t >> 6;

    int i0 = 0;
    if (mode == 0) {
        for (int idx = t; idx < HD * HD; idx += 256) fpS[idx] = fp[idx];
    } else if (mode == 1) {
        int base = (n0 < E) ? n0 : n0 - E;
        i0 = base % HD;
        for (int idx = t; idx < HD * 64; idx += 256)
            fpS[idx] = fp[(size_t)(idx >> 6) * HD + i0 + (idx & 63)];
    }
    __syncthreads();
    if (n >= 2 * E) return;
    int s = (n >= E) ? 1 : 0;
    int idd = n - s * E;
    int h = idd / HD, i = idd % HD;
    const float* W = (s ? Wk0 : Wq0) + (size_t)l * EE;
    for (int c = cg; c < E; c += 4) {
        const float* Wr = W + (size_t)c * E + h * HD;
        float acc = 0.f;
        if (mode == 0) {
            for (int d = 0; d < HD; ++d) acc += Wr[d] * fpS[d * HD + i];
        } else if (mode == 1) {
            for (int d = 0; d < HD; ++d) acc += Wr[d] * fpS[d * 64 + (i - i0)];
        } else {
            for (int d = 0; d < HD; ++d) acc += Wr[d] * fp[(size_t)d * HD + i];
        }
        Wt[(size_t)n * E + c] = bf16r(acc);
    }
}

// ---------------------------------------------------------------------------
// Batched bias fold: bqkv[l][0:E]=bq@fp, [E:2E]=bk@fp, [2E:3E]=bv
// ---------------------------------------------------------------------------
__global__ void biasfold_k(const float* __restrict__ bq0, const float* __restrict__ bk0,
                           const float* __restrict__ bv0, const float* __restrict__ fp0,
                           float* __restrict__ bqkv0, int E, int HD) {
    int l = blockIdx.z;
    const float* bq = bq0 + (size_t)l * E;
    const float* bk = bk0 + (size_t)l * E;
    const float* bv = bv0 + (size_t)l * E;
    const float* fp = fp0 + (size_t)l * HD * HD;
    float* bqkv = bqkv0 + (size_t)l * 3 * E;
    int c = blockIdx.x * 256 + threadIdx.x;
    if (c >= 3 * E) return;
    if (c < 2 * E) {
        int mat = c / E, cc = c % E, h = cc / HD, j = cc % HD;
        const float* bb = mat ? bk : bq;
        float s = 0.f;
        for (int d = 0; d < HD; ++d) s += bb[h * HD + d] * fp[(size_t)d * HD + j];
        bqkv[c] = s;
    } else {
        bqkv[c] = bv[c - 2 * E];
    }
}

// ---------------------------------------------------------------------------
// bf16 MFMA GEMM: C[M,N] = op(A[M,K] @ Bt[N,K]^T + bias)
// Tile 128x128x64, 512 thr, 8 waves (2Mx4N). Chunk-XOR swizzle on 16B units.
// Full tiles stage via global_load_lds (pre-swizzled global source, linear LDS
// dest); edge tiles use register path producing identical LDS layout.
// op: 0 f32 store, 1 gelu->bf16, 2 f32 +=, 3 bf16 store.
// ---------------------------------------------------------------------------
__global__ __launch_bounds__(512) void gemm2_k(
        const unsigned short* __restrict__ A, int lda,
        const unsigned short* __restrict__ Bt, int ldbt,
        void* __restrict__ Cv, int ldc,
        const float* __restrict__ bias,
        int M, int Nn, int K, int op, int al) {
    __shared__ unsigned short Ab[128 * 64];
    __shared__ unsigned short Bb[128 * 64];
    int t = threadIdx.x;
    int m0 = blockIdx.x * 128, n0 = blockIdx.y * 128;
    int w = t >> 6, lane = t & 63;
    int wm = w >> 2, wn = w & 3;
    int lrow = lane & 15, lk = lane >> 4;

    float4v acc[4][2];
#pragma unroll
    for (int fa = 0; fa < 4; ++fa)
#pragma unroll
        for (int fb = 0; fb < 2; ++fb) acc[fa][fb] = (float4v){0.f, 0.f, 0.f, 0.f};

    int srow8 = lane >> 3;        // row within the wave's 8-row stripe
    int sch = lane & 7;           // physical 16B slot within row
    bool fastA = al && (m0 + 128 <= M);
    bool fastB = al && (n0 + 128 <= Nn);

    for (int k0 = 0; k0 < K; k0 += 64) {
        bool fullK = (k0 + 64 <= K);
        __syncthreads();
#if USE_GLL
        if (fastA && fullK) {
#pragma unroll
            for (int it = 0; it < 2; ++it) {
                int r = w * 16 + it * 8 + srow8;
                const unsigned short* g = A + (size_t)(m0 + r) * lda + k0 + ((sch ^ (r & 7)) << 3);
                __builtin_amdgcn_global_load_lds((const void*)g, (void*)&Ab[(w * 16 + it * 8) * 64], 16, 0, 0);
            }
        } else
#endif
        {
#pragma unroll
            for (int cc = 0; cc < 2; ++cc) {
                int c = t + cc * 512;
                int row = c >> 3, ch = c & 7;
                int gm = m0 + row, gk = k0 + ch * 8;
                short8v v = {0, 0, 0, 0, 0, 0, 0, 0};
                if (gm < M) {
                    if (al && gk + 8 <= K) {
                        v = *(const short8v*)(A + (size_t)gm * lda + gk);
                    } else {
                        const unsigned short* p = A + (size_t)gm * lda;
#pragma unroll
                        for (int j = 0; j < 8; ++j)
                            if (gk + j < K) v[j] = (short)p[gk + j];
                    }
                }
                *(short8v*)&Ab[row * 64 + ((ch ^ (row & 7)) << 3)] = v;
            }
        }
#if USE_GLL
        if (fastB && fullK) {
#pragma unroll
            for (int it = 0; it < 2; ++it) {
                int r = w * 16 + it * 8 + srow8;
                const unsigned short* g = Bt + (size_t)(n0 + r) * ldbt + k0 + ((sch ^ (r & 7)) << 3);
                __builtin_amdgcn_global_load_lds((const void*)g, (void*)&Bb[(w * 16 + it * 8) * 64], 16, 0, 0);
            }
        } else
#endif
        {
#pragma unroll
            for (int cc = 0; cc < 2; ++cc) {
                int c = t + cc * 512;
                int row = c >> 3, ch = c & 7;
                int gn = n0 + row, gk = k0 + ch * 8;
                short8v v = {0, 0, 0, 0, 0, 0, 0, 0};
                if (gn < Nn) {
                    if (al && gk + 8 <= K) {
                        v = *(const short8v*)(Bt + (size_t)gn * ldbt + gk);
                    } else {
                        const unsigned short* p = Bt + (size_t)gn * ldbt;
#pragma unroll
                        for (int j = 0; j < 8; ++j)
                            if (gk + j < K) v[j] = (short)p[gk + j];
                    }
                }
                *(short8v*)&Bb[row * 64 + ((ch ^ (row & 7)) << 3)] = v;
            }
        }
        __syncthreads();
#pragma unroll
        for (int ks = 0; ks < 2; ++ks) {
            short8v af[4], bf[2];
#pragma unroll
            for (int fa = 0; fa < 4; ++fa) {
                int row = wm * 64 + fa * 16 + lrow;
                af[fa] = *(const short8v*)&Ab[row * 64 + (((ks * 4 + lk) ^ (row & 7)) << 3)];
            }
#pragma unroll
            for (int fb = 0; fb < 2; ++fb) {
                int row = wn * 32 + fb * 16 + lrow;
                bf[fb] = *(const short8v*)&Bb[row * 64 + (((ks * 4 + lk) ^ (row & 7)) << 3)];
            }
#pragma unroll
            for (int fa = 0; fa < 4; ++fa)
#pragma unroll
                for (int fb = 0; fb < 2; ++fb)
                    acc[fa][fb] = __builtin_amdgcn_mfma_f32_16x16x32_bf16(
                        af[fa], bf[fb], acc[fa][fb], 0, 0, 0);
        }
    }
    float* Cf = (float*)Cv;
    unsigned short* Cu = (unsigned short*)Cv;
#pragma unroll
    for (int fb = 0; fb < 2; ++fb) {
        int col = n0 + wn * 32 + fb * 16 + lrow;
        if (col >= Nn) continue;
        float bb = bias ? bias[col] : 0.f;
#pragma unroll
        for (int fa = 0; fa < 4; ++fa) {
#pragma unroll
            for (int q = 0; q < 4; ++q) {
                int row = m0 + wm * 64 + fa * 16 + lk * 4 + q;
                if (row >= M) continue;
                float v = acc[fa][fb][q] + bb;
                size_t idx = (size_t)row * ldc + col;
                if (op == 0) Cf[idx] = v;
                else if (op == 1) Cu[idx] = bf16r(gelu_f(v));
                else if (op == 2) Cf[idx] += v;
                else Cu[idx] = bf16r(v);
            }
        }
    }
}

// ---------------------------------------------------------------------------
// Patch embed + cls + pos -> x f32. grid (N, B), block 256.
// ---------------------------------------------------------------------------
__global__ void embed_lds_k(const float* __restrict__ src, const float* __restrict__ cw,
                            const float* __restrict__ cb, const float* __restrict__ pos,
                            const float* __restrict__ cls, float* __restrict__ x,
                            int C, int IMG, int P, int m, int E, int N, int K) {
    extern __shared__ float patch[];
    int n = blockIdx.x, b = blockIdx.y, t = threadIdx.x;
    if (n == 0) {
        for (int e = t; e < E; e += 256)
            x[((size_t)b * N) * E + e] = cls[e] + pos[e];
        return;
    }
    int p = n - 1, ph = p / m, pw = p % m;
    int P2 = P * P;
    for (int mm = t; mm < K; mm += 256) {
        int c = mm / P2, rem = mm % P2, i = rem / P, j = rem % P;
        patch[mm] = src[(((size_t)b * C + c) * IMG + ph * P + i) * IMG + pw * P + j];
    }
    __syncthreads();
    for (int e = t; e < E; e += 256) {
        float acc = cb[e];
        const float* wr = cw + (size_t)e * K;
        for (int mm = 0; mm < K; ++mm) acc += patch[mm] * wr[mm];
        x[((size_t)b * N + n) * E + e] = acc + pos[(size_t)n * E + e];
    }
}

__global__ void embed_dir_k(const float* __restrict__ src, const float* __restrict__ cw,
                            const float* __restrict__ cb, const float* __restrict__ pos,
                            const float* __restrict__ cls, float* __restrict__ x,
                            int C, int IMG, int P, int m, int E, int N, int K) {
    int n = blockIdx.x, b = blockIdx.y, t = threadIdx.x;
    if (n == 0) {
        for (int e = t; e < E; e += 256)
            x[((size_t)b * N) * E + e] = cls[e] + pos[e];
        return;
    }
    int p = n - 1, ph = p / m, pw = p % m;
    int P2 = P * P;
    for (int e = t; e < E; e += 256) {
        float acc = cb[e];
        const float* wr = cw + (size_t)e * K;
        for (int mm = 0; mm < K; ++mm) {
            int c = mm / P2, rem = mm % P2, i = rem / P, j = rem % P;
            acc += src[(((size_t)b * C + c) * IMG + ph * P + i) * IMG + pw * P + j] * wr[mm];
        }
        x[((size_t)b * N + n) * E + e] = acc + pos[(size_t)n * E + e];
    }
}

// ---------------------------------------------------------------------------
// LayerNorm rows of x f32 -> xg bf16. grid ceil(TOK/4), block 256.
// ---------------------------------------------------------------------------
__global__ void ln_k(const float* __restrict__ x, const float* __restrict__ g,
                     const float* __restrict__ b, unsigned short* __restrict__ xg,
                     int TOK, int E, float invE) {
    int row = blockIdx.x * 4 + (threadIdx.x >> 6);
    int lane = threadIdx.x & 63;
    if (row >= TOK) return;
    const float* xr = x + (size_t)row * E;
    float s = 0.f;
    for (int e = lane; e < E; e += 64) s += xr[e];
#pragma unroll
    for (int mm = 32; mm >= 1; mm >>= 1) s += __shfl_xor(s, mm, 64);
    float mean = s * invE;
    float v = 0.f;
    for (int e = lane; e < E; e += 64) { float d = xr[e] - mean; v += d * d; }
#pragma unroll
    for (int mm = 32; mm >= 1; mm >>= 1) v += __shfl_xor(v, mm, 64);
    float inv = rsqrtf(v * invE + 1e-5f);
    unsigned short* orow = xg + (size_t)row * E;
    for (int e = lane; e < E; e += 64)
        orow[e] = bf16r((xr[e] - mean) * inv * g[e] + b[e]);
}

// ---------------------------------------------------------------------------
// Attention core on bf16 qkv: scores -> softmax -> PV -> residual into x f32.
// grid (Gg, nimg), block 256. LDS: H*64 floats.
// ---------------------------------------------------------------------------
__global__ void attn_sm_k(const unsigned short* __restrict__ qkv, float* __restrict__ x,
                          int img0, int N, int E, int H, int HD, float rscale, int vec) {
    extern __shared__ float sc[];
    int g = blockIdx.x, im = blockIdx.y, t = threadIdx.x;
    int t0 = g * 8, nv = min(8, N - t0);
    int E3 = 3 * E;
    const unsigned short* qb = qkv + ((size_t)im * N + t0) * E3;
    float* xb = x + (((size_t)(img0 + im)) * N + t0) * E;
    for (int idx = t; idx < H * 64; idx += 256) {
        int h = idx >> 6, qr = (idx >> 3) & 7, kr = idx & 7;
        float s = 0.f;
        if (qr < nv && kr < nv) {
            const unsigned short* qp = qb + (size_t)qr * E3 + h * HD;
            const unsigned short* kp = qb + (size_t)kr * E3 + E + h * HD;
            if (vec) {
                for (int d = 0; d < HD; d += 8) {
                    short8v qv = *(const short8v*)(qp + d);
                    short8v kv = *(const short8v*)(kp + d);
#pragma unroll
                    for (int j = 0; j < 8; ++j)
                        s += bf2f((unsigned short)qv[j]) * bf2f((unsigned short)kv[j]);
                }
            } else {
                for (int d = 0; d < HD; ++d)
                    s += bf2f(qp[d]) * bf2f(kp[d]);
            }
        }
        sc[idx] = s * rscale;
    }
    __syncthreads();
    for (int idx = t; idx < H * 8; idx += 256) {
        int h = idx >> 3, qr = idx & 7;
        if (qr < nv) {
            float* row = sc + h * 64 + qr * 8;
            float mx = -1e30f;
            for (int k = 0; k < nv; ++k) mx = fmaxf(mx, row[k]);
            float sum = 0.f;
            for (int k = 0; k < nv; ++k) { float e = expf(row[k] - mx); row[k] = e; sum += e; }
            float inv = 1.f / sum;
            for (int k = 0; k < nv; ++k) row[k] *= inv;
        }
    }
    __syncthreads();
    for (int c = t; c < E; c += 256) {
        int h = c / HD;
        const float* srow = sc + h * 64;
        float vcol[8];
#pragma unroll
        for (int k = 0; k < 8; ++k)
            vcol[k] = (k < nv) ? bf2f(qb[(size_t)k * E3 + 2 * E + c]) : 0.f;
        for (int r = 0; r < nv; ++r) {
            float o = 0.f;
#pragma unroll
            for (int k = 0; k < 8; ++k) o += srow[r * 8 + k] * vcol[k];
            xb[(size_t)r * E + c] += o;
        }
    }
}

// ---------------------------------------------------------------------------
__global__ void head_k(const float* __restrict__ fw, const float* __restrict__ fb,
                       const float* __restrict__ x, float* __restrict__ out,
                       int Bc, int N, int E, int NC) {
    int idx = blockIdx.x * 256 + threadIdx.x;
    if (idx < Bc * NC) {
        int b = idx / NC, nc = idx % NC;
        float acc = fb[nc];
        const float* xr = x + (size_t)b * N * E;
        for (int e = 0; e < E; ++e) acc += xr[e] * fw[(size_t)e * NC + nc];
        out[idx] = acc;
    }
}

// ---------------------------------------------------------------------------
static int isqrt_i(long long v) {
    if (v < 0) return -1;
    long long r = (long long)(sqrt((double)v) + 0.5);
    while (r * r > v) --r;
    while ((r + 1) * (r + 1) <= v) ++r;
    return (int)r;
}

extern "C" void kernel_launch(void* const* d_in, const int* in_sizes, int n_in,
                              void* d_out, int out_size, void* d_ws, size_t ws_size,
                              hipStream_t stream) {
    float* out = (float*)d_out;
    int nblk_out = (out_size + 255) / 256;
#define DUMP(code, val) do { \
        dump_k<<<nblk_out, 256, 0, stream>>>(out, out_size, (float)((code) * 1000000.0 + (double)(val))); \
        return; } while (0)

    if (n_in != 22) DUMP(1, n_in < 999999 ? n_in : 999999);
    const int* S = in_sizes;

    int E = S[2];
    if (E <= 0 || S[4] != E) DUMP(2, 4);
    if (S[6] % E) DUMP(2, 6);
    int L = S[6] / E;
    if (L <= 0) DUMP(2, 6);
    long long EE = (long long)E * E;
    if (S[5] != L * EE || S[7] != L * EE || S[9] != L * EE) DUMP(2, 5);
    if (S[8] != L * E || S[10] != L * E) DUMP(2, 8);
    if (S[12] != L * E || S[13] != L * E || S[14] != L * E || S[15] != L * E) DUMP(2, 12);
    if (S[19] != L * E) DUMP(2, 19);
    if (S[11] % L) DUMP(2, 11);
    int HD = isqrt_i(S[11] / L);
    if ((long long)HD * HD * L != S[11] || HD <= 0 || E % HD) DUMP(3, HD > 0 ? HD : 0);
    int H = E / HD;
    if (S[17] % L) DUMP(2, 17);
    int FF = S[17] / L;
    if (S[16] != (long long)L * E * FF) DUMP(2, 16);
    if (S[18] != (long long)L * FF * E) DUMP(2, 18);
    if (S[3] % E) DUMP(2, 3);
    int N = S[3] / E;
    int m = isqrt_i(N - 1);
    if (m <= 0 || m * m != N - 1) DUMP(4, N < 999999 ? N : 999999);
    int NC = S[21];
    if (NC <= 0 || S[20] != (long long)E * NC) DUMP(2, 20);
    if (out_size % NC) DUMP(8, out_size < 999999 ? out_size : 999999);
    int Bc = out_size / NC;
    if (S[1] % E) DUMP(2, 1);
    int K = S[1] / E;
    static const int corder[12] = {3, 4, 1, 2, 8, 16, 6, 12, 32, 64, 24, 48};
    int C = -1, P = -1;
    for (int ci = 0; ci < 12; ++ci) {
        int c = corder[ci];
        if (K % c) continue;
        int p = isqrt_i(K / c);
        if (p > 0 && p * p * c == K) {
            long long img = (long long)p * m;
            if ((long long)Bc * c * img * img == S[0]) { C = c; P = p; break; }
        }
    }
    if (C < 0) DUMP(5, K < 999999 ? K : 999999);
    int IMG = P * m;
    int TOK = Bc * N;
    int Gg = (N + 7) / 8;
    int E3 = 3 * E;
    int al = ((E % 8) == 0 && (FF % 8) == 0) ? 1 : 0;
    int vecA = (al && (HD % 8) == 0) ? 1 : 0;

    // fold staging mode
    int fmode;
    if (HD <= 64) fmode = 0;
    else if ((E % 64) == 0 && HD <= 256) fmode = 1;
    else fmode = 2;
    size_t fold_sh = (fmode == 0) ? (size_t)HD * HD * 4
                   : (fmode == 1) ? (size_t)HD * 64 * 4 : 16;

    // ---- workspace: x | xg | Wt[LW] | w1t[LW] | w2t[LW] | bqkv[LW] | buf
    size_t b_x  = ((size_t)TOK * E * 4 + 255) & ~(size_t)255;
    size_t b_xg = ((size_t)TOK * E * 2 + 255) & ~(size_t)255;
    size_t s_wt  = ((size_t)E3 * E * 2 + 255) & ~(size_t)255;
    size_t s_wff = ((size_t)E * FF * 2 + 255) & ~(size_t)255;
    size_t s_bq  = ((size_t)E3 * 4 + 255) & ~(size_t)255;
    size_t perL = s_wt + 2 * s_wff + s_bq;
    size_t minbuf = (size_t)N * E3 * 2;
    size_t fb2 = (size_t)128 * FF * 2;
    if (fb2 > minbuf) minbuf = fb2;

    int LW;
    if (b_x + b_xg + perL * L + minbuf <= ws_size) LW = L;
    else if (b_x + b_xg + perL + minbuf <= ws_size) LW = 1;
    else { DUMP(6, (double)(ws_size >> 20)); }

    char* wsb = (char*)d_ws;
    size_t off = 0;
    float* x = (float*)(wsb + off); off += b_x;
    unsigned short* xg = (unsigned short*)(wsb + off); off += b_xg;
    unsigned short* Wt_base = (unsigned short*)(wsb + off); off += s_wt * LW;
    unsigned short* w1t_base = (unsigned short*)(wsb + off); off += s_wff * LW;
    unsigned short* w2t_base = (unsigned short*)(wsb + off); off += s_wff * LW;
    float* bq_base = (float*)(wsb + off); off += s_bq * LW;
    size_t buf_bytes = ws_size - off;
    unsigned short* bufu = (unsigned short*)(wsb + off);

    int CHI = (int)(buf_bytes / ((size_t)N * E3 * 2));
    if (CHI > Bc) CHI = Bc;
    long long chf_l = (long long)(buf_bytes / ((size_t)FF * 2));
    chf_l = (chf_l / 128) * 128;
    int CHF = chf_l > TOK ? TOK : (int)chf_l;
    if (CHI < 1 || CHF < 128) DUMP(6, (double)(ws_size >> 20));

    const float* src = (const float*)d_in[0];
    const float* cw  = (const float*)d_in[1];
    const float* cb  = (const float*)d_in[2];
    const float* pos = (const float*)d_in[3];
    const float* cls = (const float*)d_in[4];
    const float* Wq  = (const float*)d_in[5];
    const float* bq  = (const float*)d_in[6];
    const float* Wk  = (const float*)d_in[7];
    const float* bk  = (const float*)d_in[8];
    const float* Wv  = (const float*)d_in[9];
    const float* bv  = (const float*)d_in[10];
    const float* fp  = (const float*)d_in[11];
    const float* g1  = (const float*)d_in[12];
    const float* b1  = (const float*)d_in[13];
    const float* g2  = (const float*)d_in[14];
    const float* b2  = (const float*)d_in[15];
    const float* w1  = (const float*)d_in[16];
    const float* bb1 = (const float*)d_in[17];
    const float* w2  = (const float*)d_in[18];
    const float* bb2 = (const float*)d_in[19];
    const float* fcw = (const float*)d_in[20];
    const float* fcb = (const float*)d_in[21];

    float invE = 1.f / (float)E;
    float rscale = 1.f / sqrtf((float)HD);
    size_t wtL = (size_t)E3 * E;     // shorts per layer in Wt
    size_t wffL = (size_t)E * FF;    // shorts per layer in w1t/w2t

    // ---- embed (once)
    size_t patch_sh = (size_t)K * sizeof(float);
    if (patch_sh <= 48000)
        embed_lds_k<<<dim3(N, Bc), 256, patch_sh, stream>>>(src, cw, cb, pos, cls, x,
                                                            C, IMG, P, m, E, N, K);
    else
        embed_dir_k<<<dim3(N, Bc), 256, 0, stream>>>(src, cw, cb, pos, cls, x,
                                                     C, IMG, P, m, E, N, K);

    int gx_fold = (2 * E + 63) / 64;
    if (LW == L) {
        // all-layer batched prep, one launch per kernel
        fold_k<<<dim3(gx_fold, 1, L), 256, fold_sh, stream>>>(Wq, Wk, fp, Wt_base, E, HD, fmode);
        tc_k<<<dim3((E + 31) / 32, (E + 31) / 32, L), 256, 0, stream>>>(
            Wv, Wt_base + (size_t)2 * E * E, E, E, EE, wtL);
        tc_k<<<dim3((E + 31) / 32, (FF + 31) / 32, L), 256, 0, stream>>>(
            w1, w1t_base, E, FF, (long long)E * FF, wffL);
        tc_k<<<dim3((FF + 31) / 32, (E + 31) / 32, L), 256, 0, stream>>>(
            w2, w2t_base, FF, E, (long long)E * FF, wffL);
        biasfold_k<<<dim3((E3 + 255) / 256, 1, L), 256, 0, stream>>>(
            bq, bk, bv, fp, bq_base, E, HD);
    }

    int ln_grid = (TOK + 3) / 4;
    size_t attn_sh = (size_t)H * 64 * sizeof(float);

    for (int l = 0; l < L; ++l) {
        int lw = (LW == L) ? l : 0;
        unsigned short* Wt_l  = Wt_base + (size_t)lw * (s_wt / 2);
        unsigned short* w1t_l = w1t_base + (size_t)lw * (s_wff / 2);
        unsigned short* w2t_l = w2t_base + (size_t)lw * (s_wff / 2);
        float* bq_l = (float*)((char*)bq_base + (size_t)lw * s_bq);
        (void)wtL; (void)wffL;

        if (LW != L) {
            fold_k<<<dim3(gx_fold, 1, 1), 256, fold_sh, stream>>>(
                Wq + (size_t)l * EE, Wk + (size_t)l * EE, fp + (size_t)l * HD * HD,
                Wt_l, E, HD, fmode);
            tc_k<<<dim3((E + 31) / 32, (E + 31) / 32, 1), 256, 0, stream>>>(
                Wv + (size_t)l * EE, Wt_l + (size_t)2 * E * E, E, E, 0, 0);
            tc_k<<<dim3((E + 31) / 32, (FF + 31) / 32, 1), 256, 0, stream>>>(
                w1 + (size_t)l * E * FF, w1t_l, E, FF, 0, 0);
            tc_k<<<dim3((FF + 31) / 32, (E + 31) / 32, 1), 256, 0, stream>>>(
                w2 + (size_t)l * FF * E, w2t_l, FF, E, 0, 0);
            biasfold_k<<<dim3((E3 + 255) / 256, 1, 1), 256, 0, stream>>>(
                bq + (size_t)l * E, bk + (size_t)l * E, bv + (size_t)l * E,
                fp + (size_t)l * HD * HD, bq_l, E, HD);
        }

        // ---- LN1 -> xg bf16
        ln_k<<<ln_grid, 256, 0, stream>>>(x, g1 + (size_t)l * E, b1 + (size_t)l * E,
                                          xg, TOK, E, invE);
        // ---- QKV GEMM (bf16 out) + attention
        for (int img0 = 0; img0 < Bc; img0 += CHI) {
            int nimg = Bc - img0 < CHI ? Bc - img0 : CHI;
            int ntok = nimg * N;
            gemm2_k<<<dim3((ntok + 127) / 128, (E3 + 127) / 128), 512, 0, stream>>>(
                xg + (size_t)img0 * N * E, E, Wt_l, E, bufu, E3, bq_l,
                ntok, E3, E, 3, al);
            attn_sm_k<<<dim3(Gg, nimg), 256, attn_sh, stream>>>(
                bufu, x, img0, N, E, H, HD, rscale, vecA);
        }
        // ---- LN2 + FFN
        ln_k<<<ln_grid, 256, 0, stream>>>(x, g2 + (size_t)l * E, b2 + (size_t)l * E,
                                          xg, TOK, E, invE);
        for (int tok0 = 0; tok0 < TOK; tok0 += CHF) {
            int ntok = TOK - tok0 < CHF ? TOK - tok0 : CHF;
            int gx = (ntok + 127) / 128;
            gemm2_k<<<dim3(gx, (FF + 127) / 128), 512, 0, stream>>>(
                xg + (size_t)tok0 * E, E, w1t_l, E, bufu, FF,
                bb1 + (size_t)l * FF, ntok, FF, E, 1, al);
            gemm2_k<<<dim3(gx, (E + 127) / 128), 512, 0, stream>>>(
                bufu, FF, w2t_l, FF, x + (size_t)tok0 * E, E,
                bb2 + (size_t)l * E, ntok, E, FF, 2, al);
        }
    }
    head_k<<<nblk_out, 256, 0, stream>>>(fcw, fcb, x, out, Bc, N, E, NC);
#undef DUMP
}

// Round 9
// 10149.208 us; speedup vs baseline: 11.5368x; 1.0060x over previous
//
#include <hip/hip_runtime.h>
#include <math.h>

typedef __attribute__((ext_vector_type(8))) short short8v;
typedef __attribute__((ext_vector_type(4))) float float4v;

#if defined(__has_builtin)
#if __has_builtin(__builtin_amdgcn_global_load_lds)
#define USE_GLL 1
#endif
#endif
#ifndef USE_GLL
#define USE_GLL 0
#endif

__device__ __forceinline__ float gelu_f(float v) {
    return 0.5f * v * (1.0f + erff(v * 0.70710678118654752440f));
}

__device__ __forceinline__ unsigned short bf16r(float f) {
    unsigned u = __float_as_uint(f);
    u += 0x7FFFu + ((u >> 16) & 1u);
    return (unsigned short)(u >> 16);
}

__device__ __forceinline__ float bf2f(unsigned short s) {
    return __uint_as_float(((unsigned)s) << 16);
}

// ---------------------------------------------------------------------------
__global__ void dump_k(float* __restrict__ out, int n, float val) {
    int t = blockIdx.x * 256 + threadIdx.x;
    if (t < n) out[t] = val;
}

// ---------------------------------------------------------------------------
// Batched transpose-convert: in[R][Cc] f32 -> out[Cc][R] bf16; grid.z = layers.
// ---------------------------------------------------------------------------
__global__ void tc_k(const float* __restrict__ in0, unsigned short* __restrict__ out0,
                     int R, int Cc, long long ils, long long ols) {
    __shared__ float tile[32][33];
    int l = blockIdx.z;
    const float* in = in0 + (size_t)l * ils;
    unsigned short* out = out0 + (size_t)l * ols;
    int t = threadIdx.x;
    int tx = t & 31, ty = t >> 5;
    int r0 = blockIdx.x * 32, c0 = blockIdx.y * 32;
#pragma unroll
    for (int i = 0; i < 4; ++i) {
        int r = r0 + ty + i * 8, c = c0 + tx;
        tile[ty + i * 8][tx] = (r < R && c < Cc) ? in[(size_t)r * Cc + c] : 0.f;
    }
    __syncthreads();
#pragma unroll
    for (int i = 0; i < 4; ++i) {
        int c = c0 + ty + i * 8, r = r0 + tx;
        if (c < Cc && r < R) out[(size_t)c * R + r] = bf16r(tile[tx][ty + i * 8]);
    }
}

// ---------------------------------------------------------------------------
// Batched fproj fold: Wt rows n in [0,2E): n = s*E + h*HD + i
//   Wt[n][c] = sum_d Wsrc_s[c][h*HD+d] * fp[d][i],  Wsrc_0=Wq, Wsrc_1=Wk.
// grid ((2E+63)/64, 1, layers), block 256 = 64 n x 4 c-groups.
// mode: 0 = fpS[d][i] full (HD<=64), 1 = 64-wide window, 2 = direct global.
// ---------------------------------------------------------------------------
__global__ void fold_k(const float* __restrict__ Wq0, const float* __restrict__ Wk0,
                       const float* __restrict__ fp0, unsigned short* __restrict__ Wt0,
                       int E, int HD, int mode) {
    extern __shared__ float fpS[];
    int l = blockIdx.z;
    long long EE = (long long)E * E;
    const float* fp = fp0 + (size_t)l * HD * HD;
    unsigned short* Wt = Wt0 + (size_t)l * 3 * EE;
    int t = threadIdx.x;
    int n0 = blockIdx.x * 64;
    int n = n0 + (t & 63);
    int cg = t >> 6;

    int i0 = 0;
    if (mode == 0) {
        for (int idx = t; idx < HD * HD; idx += 256) fpS[idx] = fp[idx];
    } else if (mode == 1) {
        int base = (n0 < E) ? n0 : n0 - E;
        i0 = base % HD;
        for (int idx = t; idx < HD * 64; idx += 256)
            fpS[idx] = fp[(size_t)(idx >> 6) * HD + i0 + (idx & 63)];
    }
    __syncthreads();
    if (n >= 2 * E) return;
    int s = (n >= E) ? 1 : 0;
    int idd = n - s * E;
    int h = idd / HD, i = idd % HD;
    const float* W = (s ? Wk0 : Wq0) + (size_t)l * EE;
    for (int c = cg; c < E; c += 4) {
        const float* Wr = W + (size_t)c * E + h * HD;
        float acc = 0.f;
        if (mode == 0) {
            for (int d = 0; d < HD; ++d) acc += Wr[d] * fpS[d * HD + i];
        } else if (mode == 1) {
            for (int d = 0; d < HD; ++d) acc += Wr[d] * fpS[d * 64 + (i - i0)];
        } else {
            for (int d = 0; d < HD; ++d) acc += Wr[d] * fp[(size_t)d * HD + i];
        }
        Wt[(size_t)n * E + c] = bf16r(acc);
    }
}

// ---------------------------------------------------------------------------
// Batched bias fold: bqkv[l][0:E]=bq@fp, [E:2E]=bk@fp, [2E:3E]=bv
// ---------------------------------------------------------------------------
__global__ void biasfold_k(const float* __restrict__ bq0, const float* __restrict__ bk0,
                           const float* __restrict__ bv0, const float* __restrict__ fp0,
                           float* __restrict__ bqkv0, int E, int HD) {
    int l = blockIdx.z;
    const float* bq = bq0 + (size_t)l * E;
    const float* bk = bk0 + (size_t)l * E;
    const float* bv = bv0 + (size_t)l * E;
    const float* fp = fp0 + (size_t)l * HD * HD;
    float* bqkv = bqkv0 + (size_t)l * 3 * E;
    int c = blockIdx.x * 256 + threadIdx.x;
    if (c >= 3 * E) return;
    if (c < 2 * E) {
        int mat = c / E, cc = c % E, h = cc / HD, j = cc % HD;
        const float* bb = mat ? bk : bq;
        float s = 0.f;
        for (int d = 0; d < HD; ++d) s += bb[h * HD + d] * fp[(size_t)d * HD + j];
        bqkv[c] = s;
    } else {
        bqkv[c] = bv[c - 2 * E];
    }
}

// ---------------------------------------------------------------------------
// bf16 MFMA GEMM: C[M,N] = op(A[M,K] @ Bt[N,K]^T + bias)
// 1D grid = nMt*nNt blocks; bijective XCD swizzle (m204) + n-fastest decompose
// so each XCD's contiguous chunk reuses one 128-row A-panel from its L2.
// Tile 128x128x64, 512 thr, 8 waves (2Mx4N). Chunk-XOR swizzle on 16B units.
// Full tiles stage via global_load_lds (pre-swizzled global source, linear LDS
// dest); edge tiles use register path producing identical LDS layout.
// op: 0 f32 store, 1 gelu->bf16, 2 f32 +=, 3 bf16 store.
// ---------------------------------------------------------------------------
__global__ __launch_bounds__(512) void gemm2_k(
        const unsigned short* __restrict__ A, int lda,
        const unsigned short* __restrict__ Bt, int ldbt,
        void* __restrict__ Cv, int ldc,
        const float* __restrict__ bias,
        int M, int Nn, int K, int op, int al, int nNt) {
    __shared__ unsigned short Ab[128 * 64];
    __shared__ unsigned short Bb[128 * 64];
    int t = threadIdx.x;
    // bijective XCD swizzle: contiguous wgid chunk per XCD
    int nwg = gridDim.x;
    int orig = blockIdx.x;
    int xcd = orig & 7, pos = orig >> 3;
    int q = nwg >> 3, r = nwg & 7;
    int wgid = (xcd < r ? xcd * (q + 1) : r * (q + 1) + (xcd - r) * q) + pos;
    int m0 = (wgid / nNt) * 128, n0 = (wgid % nNt) * 128;
    int w = t >> 6, lane = t & 63;
    int wm = w >> 2, wn = w & 3;
    int lrow = lane & 15, lk = lane >> 4;

    float4v acc[4][2];
#pragma unroll
    for (int fa = 0; fa < 4; ++fa)
#pragma unroll
        for (int fb = 0; fb < 2; ++fb) acc[fa][fb] = (float4v){0.f, 0.f, 0.f, 0.f};

    int srow8 = lane >> 3;        // row within the wave's 8-row stripe
    int sch = lane & 7;           // physical 16B slot within row
    bool fastA = al && (m0 + 128 <= M);
    bool fastB = al && (n0 + 128 <= Nn);

    for (int k0 = 0; k0 < K; k0 += 64) {
        bool fullK = (k0 + 64 <= K);
        __syncthreads();
#if USE_GLL
        if (fastA && fullK) {
#pragma unroll
            for (int it = 0; it < 2; ++it) {
                int rr = w * 16 + it * 8 + srow8;
                const unsigned short* g = A + (size_t)(m0 + rr) * lda + k0 + ((sch ^ (rr & 7)) << 3);
                __builtin_amdgcn_global_load_lds((const void*)g, (void*)&Ab[(w * 16 + it * 8) * 64], 16, 0, 0);
            }
        } else
#endif
        {
#pragma unroll
            for (int cc = 0; cc < 2; ++cc) {
                int c = t + cc * 512;
                int row = c >> 3, ch = c & 7;
                int gm = m0 + row, gk = k0 + ch * 8;
                short8v v = {0, 0, 0, 0, 0, 0, 0, 0};
                if (gm < M) {
                    if (al && gk + 8 <= K) {
                        v = *(const short8v*)(A + (size_t)gm * lda + gk);
                    } else {
                        const unsigned short* p = A + (size_t)gm * lda;
#pragma unroll
                        for (int j = 0; j < 8; ++j)
                            if (gk + j < K) v[j] = (short)p[gk + j];
                    }
                }
                *(short8v*)&Ab[row * 64 + ((ch ^ (row & 7)) << 3)] = v;
            }
        }
#if USE_GLL
        if (fastB && fullK) {
#pragma unroll
            for (int it = 0; it < 2; ++it) {
                int rr = w * 16 + it * 8 + srow8;
                const unsigned short* g = Bt + (size_t)(n0 + rr) * ldbt + k0 + ((sch ^ (rr & 7)) << 3);
                __builtin_amdgcn_global_load_lds((const void*)g, (void*)&Bb[(w * 16 + it * 8) * 64], 16, 0, 0);
            }
        } else
#endif
        {
#pragma unroll
            for (int cc = 0; cc < 2; ++cc) {
                int c = t + cc * 512;
                int row = c >> 3, ch = c & 7;
                int gn = n0 + row, gk = k0 + ch * 8;
                short8v v = {0, 0, 0, 0, 0, 0, 0, 0};
                if (gn < Nn) {
                    if (al && gk + 8 <= K) {
                        v = *(const short8v*)(Bt + (size_t)gn * ldbt + gk);
                    } else {
                        const unsigned short* p = Bt + (size_t)gn * ldbt;
#pragma unroll
                        for (int j = 0; j < 8; ++j)
                            if (gk + j < K) v[j] = (short)p[gk + j];
                    }
                }
                *(short8v*)&Bb[row * 64 + ((ch ^ (row & 7)) << 3)] = v;
            }
        }
        __syncthreads();
#pragma unroll
        for (int ks = 0; ks < 2; ++ks) {
            short8v af[4], bf[2];
#pragma unroll
            for (int fa = 0; fa < 4; ++fa) {
                int row = wm * 64 + fa * 16 + lrow;
                af[fa] = *(const short8v*)&Ab[row * 64 + (((ks * 4 + lk) ^ (row & 7)) << 3)];
            }
#pragma unroll
            for (int fb = 0; fb < 2; ++fb) {
                int row = wn * 32 + fb * 16 + lrow;
                bf[fb] = *(const short8v*)&Bb[row * 64 + (((ks * 4 + lk) ^ (row & 7)) << 3)];
            }
#pragma unroll
            for (int fa = 0; fa < 4; ++fa)
#pragma unroll
                for (int fb = 0; fb < 2; ++fb)
                    acc[fa][fb] = __builtin_amdgcn_mfma_f32_16x16x32_bf16(
                        af[fa], bf[fb], acc[fa][fb], 0, 0, 0);
        }
    }
    float* Cf = (float*)Cv;
    unsigned short* Cu = (unsigned short*)Cv;
#pragma unroll
    for (int fb = 0; fb < 2; ++fb) {
        int col = n0 + wn * 32 + fb * 16 + lrow;
        if (col >= Nn) continue;
        float bb = bias ? bias[col] : 0.f;
#pragma unroll
        for (int fa = 0; fa < 4; ++fa) {
#pragma unroll
            for (int q2 = 0; q2 < 4; ++q2) {
                int row = m0 + wm * 64 + fa * 16 + lk * 4 + q2;
                if (row >= M) continue;
                float v = acc[fa][fb][q2] + bb;
                size_t idx = (size_t)row * ldc + col;
                if (op == 0) Cf[idx] = v;
                else if (op == 1) Cu[idx] = bf16r(gelu_f(v));
                else if (op == 2) Cf[idx] += v;
                else Cu[idx] = bf16r(v);
            }
        }
    }
}

// ---------------------------------------------------------------------------
// Patch embed + cls + pos -> x f32. grid (N, B), block 256.
// ---------------------------------------------------------------------------
__global__ void embed_lds_k(const float* __restrict__ src, const float* __restrict__ cw,
                            const float* __restrict__ cb, const float* __restrict__ pos,
                            const float* __restrict__ cls, float* __restrict__ x,
                            int C, int IMG, int P, int m, int E, int N, int K) {
    extern __shared__ float patch[];
    int n = blockIdx.x, b = blockIdx.y, t = threadIdx.x;
    if (n == 0) {
        for (int e = t; e < E; e += 256)
            x[((size_t)b * N) * E + e] = cls[e] + pos[e];
        return;
    }
    int p = n - 1, ph = p / m, pw = p % m;
    int P2 = P * P;
    for (int mm = t; mm < K; mm += 256) {
        int c = mm / P2, rem = mm % P2, i = rem / P, j = rem % P;
        patch[mm] = src[(((size_t)b * C + c) * IMG + ph * P + i) * IMG + pw * P + j];
    }
    __syncthreads();
    for (int e = t; e < E; e += 256) {
        float acc = cb[e];
        const float* wr = cw + (size_t)e * K;
        for (int mm = 0; mm < K; ++mm) acc += patch[mm] * wr[mm];
        x[((size_t)b * N + n) * E + e] = acc + pos[(size_t)n * E + e];
    }
}

__global__ void embed_dir_k(const float* __restrict__ src, const float* __restrict__ cw,
                            const float* __restrict__ cb, const float* __restrict__ pos,
                            const float* __restrict__ cls, float* __restrict__ x,
                            int C, int IMG, int P, int m, int E, int N, int K) {
    int n = blockIdx.x, b = blockIdx.y, t = threadIdx.x;
    if (n == 0) {
        for (int e = t; e < E; e += 256)
            x[((size_t)b * N) * E + e] = cls[e] + pos[e];
        return;
    }
    int p = n - 1, ph = p / m, pw = p % m;
    int P2 = P * P;
    for (int e = t; e < E; e += 256) {
        float acc = cb[e];
        const float* wr = cw + (size_t)e * K;
        for (int mm = 0; mm < K; ++mm) {
            int c = mm / P2, rem = mm % P2, i = rem / P, j = rem % P;
            acc += src[(((size_t)b * C + c) * IMG + ph * P + i) * IMG + pw * P + j] * wr[mm];
        }
        x[((size_t)b * N + n) * E + e] = acc + pos[(size_t)n * E + e];
    }
}

// ---------------------------------------------------------------------------
// LayerNorm rows of x f32 -> xg bf16. grid ceil(TOK/4), block 256.
// ---------------------------------------------------------------------------
__global__ void ln_k(const float* __restrict__ x, const float* __restrict__ g,
                     const float* __restrict__ b, unsigned short* __restrict__ xg,
                     int TOK, int E, float invE) {
    int row = blockIdx.x * 4 + (threadIdx.x >> 6);
    int lane = threadIdx.x & 63;
    if (row >= TOK) return;
    const float* xr = x + (size_t)row * E;
    float s = 0.f;
    for (int e = lane; e < E; e += 64) s += xr[e];
#pragma unroll
    for (int mm = 32; mm >= 1; mm >>= 1) s += __shfl_xor(s, mm, 64);
    float mean = s * invE;
    float v = 0.f;
    for (int e = lane; e < E; e += 64) { float d = xr[e] - mean; v += d * d; }
#pragma unroll
    for (int mm = 32; mm >= 1; mm >>= 1) v += __shfl_xor(v, mm, 64);
    float inv = rsqrtf(v * invE + 1e-5f);
    unsigned short* orow = xg + (size_t)row * E;
    for (int e = lane; e < E; e += 64)
        orow[e] = bf16r((xr[e] - mean) * inv * g[e] + b[e]);
}

// ---------------------------------------------------------------------------
// Attention core on bf16 qkv + FUSED LN2: scores -> softmax -> PV -> residual
// into x f32 -> LN2 -> xg bf16.  grid (Gg, nimg), block 256. LDS: H*64 floats.
// After the residual barrier, wave w LNs rows {w, w+4} via wave-local shuffle
// reduce (no extra barriers).
// ---------------------------------------------------------------------------
__global__ void attn_sm_k(const unsigned short* __restrict__ qkv, float* __restrict__ x,
                          unsigned short* __restrict__ xg,
                          const float* __restrict__ g2, const float* __restrict__ b2,
                          int img0, int N, int E, int H, int HD, float rscale,
                          float invE, int vec) {
    extern __shared__ float sc[];
    int g = blockIdx.x, im = blockIdx.y, t = threadIdx.x;
    int t0 = g * 8, nv = min(8, N - t0);
    int E3 = 3 * E;
    const unsigned short* qb = qkv + ((size_t)im * N + t0) * E3;
    size_t rowbase = ((size_t)(img0 + im)) * N + t0;
    float* xb = x + rowbase * E;
    for (int idx = t; idx < H * 64; idx += 256) {
        int h = idx >> 6, qr = (idx >> 3) & 7, kr = idx & 7;
        float s = 0.f;
        if (qr < nv && kr < nv) {
            const unsigned short* qp = qb + (size_t)qr * E3 + h * HD;
            const unsigned short* kp = qb + (size_t)kr * E3 + E + h * HD;
            if (vec) {
                for (int d = 0; d < HD; d += 8) {
                    short8v qv = *(const short8v*)(qp + d);
                    short8v kv = *(const short8v*)(kp + d);
#pragma unroll
                    for (int j = 0; j < 8; ++j)
                        s += bf2f((unsigned short)qv[j]) * bf2f((unsigned short)kv[j]);
                }
            } else {
                for (int d = 0; d < HD; ++d)
                    s += bf2f(qp[d]) * bf2f(kp[d]);
            }
        }
        sc[idx] = s * rscale;
    }
    __syncthreads();
    for (int idx = t; idx < H * 8; idx += 256) {
        int h = idx >> 3, qr = idx & 7;
        if (qr < nv) {
            float* row = sc + h * 64 + qr * 8;
            float mx = -1e30f;
            for (int k = 0; k < nv; ++k) mx = fmaxf(mx, row[k]);
            float sum = 0.f;
            for (int k = 0; k < nv; ++k) { float e = expf(row[k] - mx); row[k] = e; sum += e; }
            float inv = 1.f / sum;
            for (int k = 0; k < nv; ++k) row[k] *= inv;
        }
    }
    __syncthreads();
    for (int c = t; c < E; c += 256) {
        int h = c / HD;
        const float* srow = sc + h * 64;
        float vcol[8];
#pragma unroll
        for (int k = 0; k < 8; ++k)
            vcol[k] = (k < nv) ? bf2f(qb[(size_t)k * E3 + 2 * E + c]) : 0.f;
        for (int r = 0; r < nv; ++r) {
            float o = 0.f;
#pragma unroll
            for (int k = 0; k < 8; ++k) o += srow[r * 8 + k] * vcol[k];
            xb[(size_t)r * E + c] += o;
        }
    }
    __syncthreads();   // residual writes visible block-wide
    // ---- fused LN2: wave w handles rows w and w+4
    int w = t >> 6, lane = t & 63;
#pragma unroll
    for (int rr = 0; rr < 2; ++rr) {
        int r = w + rr * 4;
        if (r >= nv) continue;
        const float* xr = xb + (size_t)r * E;
        float s = 0.f;
        for (int e = lane; e < E; e += 64) s += xr[e];
#pragma unroll
        for (int mm = 32; mm >= 1; mm >>= 1) s += __shfl_xor(s, mm, 64);
        float mean = s * invE;
        float v = 0.f;
        for (int e = lane; e < E; e += 64) { float d = xr[e] - mean; v += d * d; }
#pragma unroll
        for (int mm = 32; mm >= 1; mm >>= 1) v += __shfl_xor(v, mm, 64);
        float inv = rsqrtf(v * invE + 1e-5f);
        unsigned short* orow = xg + (rowbase + r) * E;
        for (int e = lane; e < E; e += 64)
            orow[e] = bf16r((xr[e] - mean) * inv * g2[e] + b2[e]);
    }
}

// ---------------------------------------------------------------------------
__global__ void head_k(const float* __restrict__ fw, const float* __restrict__ fb,
                       const float* __restrict__ x, float* __restrict__ out,
                       int Bc, int N, int E, int NC) {
    int idx = blockIdx.x * 256 + threadIdx.x;
    if (idx < Bc * NC) {
        int b = idx / NC, nc = idx % NC;
        float acc = fb[nc];
        const float* xr = x + (size_t)b * N * E;
        for (int e = 0; e < E; ++e) acc += xr[e] * fw[(size_t)e * NC + nc];
        out[idx] = acc;
    }
}

// ---------------------------------------------------------------------------
static int isqrt_i(long long v) {
    if (v < 0) return -1;
    long long r = (long long)(sqrt((double)v) + 0.5);
    while (r * r > v) --r;
    while ((r + 1) * (r + 1) <= v) ++r;
    return (int)r;
}

extern "C" void kernel_launch(void* const* d_in, const int* in_sizes, int n_in,
                              void* d_out, int out_size, void* d_ws, size_t ws_size,
                              hipStream_t stream) {
    float* out = (float*)d_out;
    int nblk_out = (out_size + 255) / 256;
#define DUMP(code, val) do { \
        dump_k<<<nblk_out, 256, 0, stream>>>(out, out_size, (float)((code) * 1000000.0 + (double)(val))); \
        return; } while (0)

    if (n_in != 22) DUMP(1, n_in < 999999 ? n_in : 999999);
    const int* S = in_sizes;

    int E = S[2];
    if (E <= 0 || S[4] != E) DUMP(2, 4);
    if (S[6] % E) DUMP(2, 6);
    int L = S[6] / E;
    if (L <= 0) DUMP(2, 6);
    long long EE = (long long)E * E;
    if (S[5] != L * EE || S[7] != L * EE || S[9] != L * EE) DUMP(2, 5);
    if (S[8] != L * E || S[10] != L * E) DUMP(2, 8);
    if (S[12] != L * E || S[13] != L * E || S[14] != L * E || S[15] != L * E) DUMP(2, 12);
    if (S[19] != L * E) DUMP(2, 19);
    if (S[11] % L) DUMP(2, 11);
    int HD = isqrt_i(S[11] / L);
    if ((long long)HD * HD * L != S[11] || HD <= 0 || E % HD) DUMP(3, HD > 0 ? HD : 0);
    int H = E / HD;
    if (S[17] % L) DUMP(2, 17);
    int FF = S[17] / L;
    if (S[16] != (long long)L * E * FF) DUMP(2, 16);
    if (S[18] != (long long)L * FF * E) DUMP(2, 18);
    if (S[3] % E) DUMP(2, 3);
    int N = S[3] / E;
    int m = isqrt_i(N - 1);
    if (m <= 0 || m * m != N - 1) DUMP(4, N < 999999 ? N : 999999);
    int NC = S[21];
    if (NC <= 0 || S[20] != (long long)E * NC) DUMP(2, 20);
    if (out_size % NC) DUMP(8, out_size < 999999 ? out_size : 999999);
    int Bc = out_size / NC;
    if (S[1] % E) DUMP(2, 1);
    int K = S[1] / E;
    static const int corder[12] = {3, 4, 1, 2, 8, 16, 6, 12, 32, 64, 24, 48};
    int C = -1, P = -1;
    for (int ci = 0; ci < 12; ++ci) {
        int c = corder[ci];
        if (K % c) continue;
        int p = isqrt_i(K / c);
        if (p > 0 && p * p * c == K) {
            long long img = (long long)p * m;
            if ((long long)Bc * c * img * img == S[0]) { C = c; P = p; break; }
        }
    }
    if (C < 0) DUMP(5, K < 999999 ? K : 999999);
    int IMG = P * m;
    int TOK = Bc * N;
    int Gg = (N + 7) / 8;
    int E3 = 3 * E;
    int al = ((E % 8) == 0 && (FF % 8) == 0) ? 1 : 0;
    int vecA = (al && (HD % 8) == 0) ? 1 : 0;

    // fold staging mode
    int fmode;
    if (HD <= 64) fmode = 0;
    else if ((E % 64) == 0 && HD <= 256) fmode = 1;
    else fmode = 2;
    size_t fold_sh = (fmode == 0) ? (size_t)HD * HD * 4
                   : (fmode == 1) ? (size_t)HD * 64 * 4 : 16;

    // ---- workspace: x | xg | Wt[LW] | w1t[LW] | w2t[LW] | bqkv[LW] | buf
    size_t b_x  = ((size_t)TOK * E * 4 + 255) & ~(size_t)255;
    size_t b_xg = ((size_t)TOK * E * 2 + 255) & ~(size_t)255;
    size_t s_wt  = ((size_t)E3 * E * 2 + 255) & ~(size_t)255;
    size_t s_wff = ((size_t)E * FF * 2 + 255) & ~(size_t)255;
    size_t s_bq  = ((size_t)E3 * 4 + 255) & ~(size_t)255;
    size_t perL = s_wt + 2 * s_wff + s_bq;
    size_t minbuf = (size_t)N * E3 * 2;
    size_t fb2 = (size_t)128 * FF * 2;
    if (fb2 > minbuf) minbuf = fb2;

    int LW;
    if (b_x + b_xg + perL * L + minbuf <= ws_size) LW = L;
    else if (b_x + b_xg + perL + minbuf <= ws_size) LW = 1;
    else { DUMP(6, (double)(ws_size >> 20)); }

    char* wsb = (char*)d_ws;
    size_t off = 0;
    float* x = (float*)(wsb + off); off += b_x;
    unsigned short* xg = (unsigned short*)(wsb + off); off += b_xg;
    unsigned short* Wt_base = (unsigned short*)(wsb + off); off += s_wt * LW;
    unsigned short* w1t_base = (unsigned short*)(wsb + off); off += s_wff * LW;
    unsigned short* w2t_base = (unsigned short*)(wsb + off); off += s_wff * LW;
    float* bq_base = (float*)(wsb + off); off += s_bq * LW;
    size_t buf_bytes = ws_size - off;
    unsigned short* bufu = (unsigned short*)(wsb + off);

    int CHI = (int)(buf_bytes / ((size_t)N * E3 * 2));
    if (CHI > Bc) CHI = Bc;
    long long chf_l = (long long)(buf_bytes / ((size_t)FF * 2));
    chf_l = (chf_l / 128) * 128;
    int CHF = chf_l > TOK ? TOK : (int)chf_l;
    if (CHI < 1 || CHF < 128) DUMP(6, (double)(ws_size >> 20));

    const float* src = (const float*)d_in[0];
    const float* cw  = (const float*)d_in[1];
    const float* cb  = (const float*)d_in[2];
    const float* pos = (const float*)d_in[3];
    const float* cls = (const float*)d_in[4];
    const float* Wq  = (const float*)d_in[5];
    const float* bq  = (const float*)d_in[6];
    const float* Wk  = (const float*)d_in[7];
    const float* bk  = (const float*)d_in[8];
    const float* Wv  = (const float*)d_in[9];
    const float* bv  = (const float*)d_in[10];
    const float* fp  = (const float*)d_in[11];
    const float* g1  = (const float*)d_in[12];
    const float* b1  = (const float*)d_in[13];
    const float* g2  = (const float*)d_in[14];
    const float* b2  = (const float*)d_in[15];
    const float* w1  = (const float*)d_in[16];
    const float* bb1 = (const float*)d_in[17];
    const float* w2  = (const float*)d_in[18];
    const float* bb2 = (const float*)d_in[19];
    const float* fcw = (const float*)d_in[20];
    const float* fcb = (const float*)d_in[21];

    float invE = 1.f / (float)E;
    float rscale = 1.f / sqrtf((float)HD);
    size_t wtL = (size_t)E3 * E;
    size_t wffL = (size_t)E * FF;

    // ---- embed (once)
    size_t patch_sh = (size_t)K * sizeof(float);
    if (patch_sh <= 48000)
        embed_lds_k<<<dim3(N, Bc), 256, patch_sh, stream>>>(src, cw, cb, pos, cls, x,
                                                            C, IMG, P, m, E, N, K);
    else
        embed_dir_k<<<dim3(N, Bc), 256, 0, stream>>>(src, cw, cb, pos, cls, x,
                                                     C, IMG, P, m, E, N, K);

    int gx_fold = (2 * E + 63) / 64;
    if (LW == L) {
        fold_k<<<dim3(gx_fold, 1, L), 256, fold_sh, stream>>>(Wq, Wk, fp, Wt_base, E, HD, fmode);
        tc_k<<<dim3((E + 31) / 32, (E + 31) / 32, L), 256, 0, stream>>>(
            Wv, Wt_base + (size_t)2 * E * E, E, E, EE, wtL);
        tc_k<<<dim3((E + 31) / 32, (FF + 31) / 32, L), 256, 0, stream>>>(
            w1, w1t_base, E, FF, (long long)E * FF, wffL);
        tc_k<<<dim3((FF + 31) / 32, (E + 31) / 32, L), 256, 0, stream>>>(
            w2, w2t_base, FF, E, (long long)E * FF, wffL);
        biasfold_k<<<dim3((E3 + 255) / 256, 1, L), 256, 0, stream>>>(
            bq, bk, bv, fp, bq_base, E, HD);
    }

    int ln_grid = (TOK + 3) / 4;
    size_t attn_sh = (size_t)H * 64 * sizeof(float);

    for (int l = 0; l < L; ++l) {
        int lw = (LW == L) ? l : 0;
        unsigned short* Wt_l  = Wt_base + (size_t)lw * (s_wt / 2);
        unsigned short* w1t_l = w1t_base + (size_t)lw * (s_wff / 2);
        unsigned short* w2t_l = w2t_base + (size_t)lw * (s_wff / 2);
        float* bq_l = (float*)((char*)bq_base + (size_t)lw * s_bq);

        if (LW != L) {
            fold_k<<<dim3(gx_fold, 1, 1), 256, fold_sh, stream>>>(
                Wq + (size_t)l * EE, Wk + (size_t)l * EE, fp + (size_t)l * HD * HD,
                Wt_l, E, HD, fmode);
            tc_k<<<dim3((E + 31) / 32, (E + 31) / 32, 1), 256, 0, stream>>>(
                Wv + (size_t)l * EE, Wt_l + (size_t)2 * E * E, E, E, 0, 0);
            tc_k<<<dim3((E + 31) / 32, (FF + 31) / 32, 1), 256, 0, stream>>>(
                w1 + (size_t)l * E * FF, w1t_l, E, FF, 0, 0);
            tc_k<<<dim3((FF + 31) / 32, (E + 31) / 32, 1), 256, 0, stream>>>(
                w2 + (size_t)l * FF * E, w2t_l, FF, E, 0, 0);
            biasfold_k<<<dim3((E3 + 255) / 256, 1, 1), 256, 0, stream>>>(
                bq + (size_t)l * E, bk + (size_t)l * E, bv + (size_t)l * E,
                fp + (size_t)l * HD * HD, bq_l, E, HD);
        }

        // ---- LN1 -> xg bf16
        ln_k<<<ln_grid, 256, 0, stream>>>(x, g1 + (size_t)l * E, b1 + (size_t)l * E,
                                          xg, TOK, E, invE);
        // ---- QKV GEMM (bf16 out) + attention (+ fused LN2 -> xg)
        for (int img0 = 0; img0 < Bc; img0 += CHI) {
            int nimg = Bc - img0 < CHI ? Bc - img0 : CHI;
            int ntok = nimg * N;
            int nMt = (ntok + 127) / 128, nNt = (E3 + 127) / 128;
            gemm2_k<<<nMt * nNt, 512, 0, stream>>>(
                xg + (size_t)img0 * N * E, E, Wt_l, E, bufu, E3, bq_l,
                ntok, E3, E, 3, al, nNt);
            attn_sm_k<<<dim3(Gg, nimg), 256, attn_sh, stream>>>(
                bufu, x, xg, g2 + (size_t)l * E, b2 + (size_t)l * E,
                img0, N, E, H, HD, rscale, invE, vecA);
        }
        // ---- FFN (xg already = LN2(x))
        for (int tok0 = 0; tok0 < TOK; tok0 += CHF) {
            int ntok = TOK - tok0 < CHF ? TOK - tok0 : CHF;
            int nMt = (ntok + 127) / 128;
            int nNt1 = (FF + 127) / 128, nNt2 = (E + 127) / 128;
            gemm2_k<<<nMt * nNt1, 512, 0, stream>>>(
                xg + (size_t)tok0 * E, E, w1t_l, E, bufu, FF,
                bb1 + (size_t)l * FF, ntok, FF, E, 1, al, nNt1);
            gemm2_k<<<nMt * nNt2, 512, 0, stream>>>(
                bufu, FF, w2t_l, FF, x + (size_t)tok0 * E, E,
                bb2 + (size_t)l * E, ntok, E, FF, 2, al, nNt2);
        }
    }
    head_k<<<nblk_out, 256, 0, stream>>>(fcw, fcb, x, out, Bc, N, E, NC);
#undef DUMP
}